// Round 1
// baseline (544.068 us; speedup 1.0000x reference)
//
#include <hip/hip_runtime.h>
#include <stdint.h>

typedef __bf16 bf16_t;
typedef __bf16 bf16x4_t __attribute__((ext_vector_type(4)));
typedef __bf16 bf16x8_t __attribute__((ext_vector_type(8)));
typedef float  f32x4_t  __attribute__((ext_vector_type(4)));

#define S_LEN 2048
#define DMODEL 1024
#define NHEAD 16
#define HDIM 64
#define MTOT 4096   // B*S

__device__ __forceinline__ f32x4_t mfma16(bf16x8_t a, bf16x8_t b, f32x4_t c){
  return __builtin_amdgcn_mfma_f32_16x16x32_bf16(a, b, c, 0, 0, 0);
}

__device__ __forceinline__ void gload_lds16(const bf16_t* g, bf16_t* l){
  __builtin_amdgcn_global_load_lds(
      (const __attribute__((address_space(1))) void*)(uintptr_t)g,
      (__attribute__((address_space(3))) void*)(uintptr_t)l,
      16, 0, 0);
}

// Stage a [ROWS][64] bf16 tile into linear LDS. 256 threads / 4 waves.
// LDS dest is wave-uniform base (+ lane*16B in HW); global src per-lane.
template<int ROWS>
__device__ __forceinline__ void stage_tile(bf16_t* lds, const bf16_t* __restrict__ g,
                                           int ldg, int wid, int lane){
#pragma unroll
  for (int it = 0; it < ROWS/32; ++it){
    const int chunk = it*4 + wid;
    const int base  = chunk*512;          // elements, wave-uniform
    const int le    = base + lane*8;      // this lane's first element
    const int r = le >> 6, c = le & 63;
    gload_lds16(g + (size_t)r*ldg + c, lds + base);
  }
}

// ---------------- K0: f32 -> bf16 hi/lo split ----------------
__global__ __launch_bounds__(256)
void vsa_split_kernel(const float* __restrict__ src, bf16_t* __restrict__ hi,
                      bf16_t* __restrict__ lo, int n4){
  int i = blockIdx.x*256 + threadIdx.x;
  if (i >= n4) return;
  float4 v = ((const float4*)src)[i];
  bf16_t h0=(bf16_t)v.x, h1=(bf16_t)v.y, h2=(bf16_t)v.z, h3=(bf16_t)v.w;
  bf16x4_t hv = {h0,h1,h2,h3};
  bf16x4_t lv = {(bf16_t)(v.x-(float)h0),(bf16_t)(v.y-(float)h1),
                 (bf16_t)(v.z-(float)h2),(bf16_t)(v.w-(float)h3)};
  ((bf16x4_t*)hi)[i] = hv;
  ((bf16x4_t*)lo)[i] = lv;
}

// ---------------- K1: QKV projection, split-bf16 (3-MFMA) GEMM ----------------
// C[m,n] = sum_k x[m,k] * W[n,k]; 128x128 tile, BK=64, 4 waves, 4x4 accs/wave.
__global__ __launch_bounds__(256)
void vsa_qkv_kernel(const bf16_t* __restrict__ xhi, const bf16_t* __restrict__ xlo,
                    const bf16_t* __restrict__ Whi, const bf16_t* __restrict__ Wlo,
                    bf16_t* __restrict__ Qb, bf16_t* __restrict__ Q2b,
                    bf16_t* __restrict__ Kb, bf16_t* __restrict__ K2b,
                    bf16_t* __restrict__ Vtb)
{
  __shared__ __align__(16) bf16_t Ah[128][64], Al[128][64], Bh[128][64], Bl[128][64];
  const int z  = blockIdx.z;                 // 0=Q,1=K,2=V
  const int m0 = blockIdx.x * 128;
  const int n0 = blockIdx.y * 128;
  const int tid = threadIdx.x, lane = tid & 63, wid = tid >> 6;
  const int wr = (wid >> 1) * 64, wc = (wid & 1) * 64;
  const bf16_t* Wh = Whi + (size_t)z * (DMODEL*DMODEL);
  const bf16_t* Wl = Wlo + (size_t)z * (DMODEL*DMODEL);

  const f32x4_t zz = {0.f,0.f,0.f,0.f};
  f32x4_t acc[4][4];
#pragma unroll
  for (int i=0;i<4;i++)
#pragma unroll
    for (int j=0;j<4;j++) acc[i][j] = zz;

  for (int kt = 0; kt < 16; ++kt){
    const int k0 = kt * 64;
    stage_tile<128>(&Ah[0][0], xhi + (size_t)m0*DMODEL + k0, DMODEL, wid, lane);
    stage_tile<128>(&Al[0][0], xlo + (size_t)m0*DMODEL + k0, DMODEL, wid, lane);
    stage_tile<128>(&Bh[0][0], Wh  + (size_t)n0*DMODEL + k0, DMODEL, wid, lane);
    stage_tile<128>(&Bl[0][0], Wl  + (size_t)n0*DMODEL + k0, DMODEL, wid, lane);
    __syncthreads();
#pragma unroll
    for (int kk = 0; kk < 2; ++kk){
      const int ko = kk*32 + (lane>>4)*8;
      bf16x8_t ah[4], al[4], bh4[4], bl4[4];
#pragma unroll
      for (int i=0;i<4;i++){
        ah[i]  = *(const bf16x8_t*)&Ah[wr + i*16 + (lane&15)][ko];
        al[i]  = *(const bf16x8_t*)&Al[wr + i*16 + (lane&15)][ko];
        bh4[i] = *(const bf16x8_t*)&Bh[wc + i*16 + (lane&15)][ko];
        bl4[i] = *(const bf16x8_t*)&Bl[wc + i*16 + (lane&15)][ko];
      }
#pragma unroll
      for (int i=0;i<4;i++)
#pragma unroll
        for (int j=0;j<4;j++){
          acc[i][j] = mfma16(ah[i], bh4[j], acc[i][j]);
          acc[i][j] = mfma16(ah[i], bl4[j], acc[i][j]);
          acc[i][j] = mfma16(al[i], bh4[j], acc[i][j]);
        }
    }
    __syncthreads();
  }

#pragma unroll
  for (int i=0;i<4;i++)
#pragma unroll
    for (int j=0;j<4;j++)
#pragma unroll
      for (int r=0;r<4;r++){
        const int m = m0 + wr + i*16 + ((lane>>4)<<2) + r;
        const int n = n0 + wc + j*16 + (lane&15);
        const float q = acc[i][j][r];
        const int b = m >> 11, s = m & 2047, h = n >> 6, d = n & 63;
        const size_t bh_ = (size_t)b*NHEAD + h;
        if (z == 0){
          const size_t o = (bh_*S_LEN + s)*HDIM + d;
          Qb[o] = (bf16_t)q; Q2b[o] = (bf16_t)(q*q);
        } else if (z == 1){
          const size_t o = (bh_*S_LEN + s)*HDIM + d;
          Kb[o] = (bf16_t)q; K2b[o] = (bf16_t)(q*q);
        } else {
          Vtb[(bh_*HDIM + d)*S_LEN + s] = (bf16_t)q;   // V stored transposed [64][S]
        }
      }
}

// ---------------- K2: attention (two-pass exact softmax + PV) ----------------
// 1 WG = (b,h, 64-row q-tile). 4 waves; wave w owns q-rows [w*16, w*16+16).
__global__ __launch_bounds__(256)
void vsa_attn_kernel(const bf16_t* __restrict__ Qb, const bf16_t* __restrict__ Q2b,
                     const bf16_t* __restrict__ Kb, const bf16_t* __restrict__ K2b,
                     const bf16_t* __restrict__ Vtb,
                     float* __restrict__ Wout,
                     bf16_t* __restrict__ o1hi, bf16_t* __restrict__ o1lo)
{
  __shared__ __align__(16) bf16_t Qs[64][64], Q2s[64][64], Ks[64][64], K2s[64][64], Vts[64][64];
  __shared__ __align__(16) bf16_t Ws[4][16][64];

  const int qt = blockIdx.x;       // 0..31
  const int bh = blockIdx.y;       // 0..31
  const int tid = threadIdx.x, lane = tid & 63, wid = tid >> 6;
  const size_t base = (size_t)bh * (S_LEN*HDIM);
  const bf16_t* Qg  = Qb  + base + (size_t)qt*64*HDIM;
  const bf16_t* Q2g = Q2b + base + (size_t)qt*64*HDIM;
  const bf16_t* Kg  = Kb  + base;
  const bf16_t* K2g = K2b + base;
  const bf16_t* Vg  = Vtb + base;   // [64][2048]

  stage_tile<64>(&Qs[0][0],  Qg,  HDIM, wid, lane);
  stage_tile<64>(&Q2s[0][0], Q2g, HDIM, wid, lane);

  const int qr = lane & 15;        // A-frag / B-frag row index
  const int cg = lane >> 4;        // k-group; C row = cg*4 + r
  float mrow[4], lrow[4];
#pragma unroll
  for (int r=0;r<4;r++){ mrow[r] = -1e30f; lrow[r] = 0.f; }

  const f32x4_t zz = {0.f,0.f,0.f,0.f};

  // ---- pass 1: softmax stats (m, l) ----
  for (int jt = 0; jt < 32; ++jt){
    stage_tile<64>(&Ks[0][0],  Kg  + (size_t)jt*64*HDIM, HDIM, wid, lane);
    stage_tile<64>(&K2s[0][0], K2g + (size_t)jt*64*HDIM, HDIM, wid, lane);
    __syncthreads();
    f32x4_t num[4], nrm[4];
#pragma unroll
    for (int n=0;n<4;n++){ num[n]=zz; nrm[n]=zz; }
#pragma unroll
    for (int kk=0;kk<2;kk++){
      const int ko = kk*32 + cg*8;
      bf16x8_t aq  = *(const bf16x8_t*)&Qs [wid*16 + qr][ko];
      bf16x8_t aq2 = *(const bf16x8_t*)&Q2s[wid*16 + qr][ko];
#pragma unroll
      for (int n=0;n<4;n++){
        num[n] = mfma16(aq,  *(const bf16x8_t*)&Ks [n*16 + qr][ko], num[n]);
        nrm[n] = mfma16(aq2, *(const bf16x8_t*)&K2s[n*16 + qr][ko], nrm[n]);
      }
    }
#pragma unroll
    for (int r=0;r<4;r++){
      float s0 = num[0][r]*rsqrtf(fmaxf(nrm[0][r],1e-16f))*0.125f;
      float s1 = num[1][r]*rsqrtf(fmaxf(nrm[1][r],1e-16f))*0.125f;
      float s2 = num[2][r]*rsqrtf(fmaxf(nrm[2][r],1e-16f))*0.125f;
      float s3 = num[3][r]*rsqrtf(fmaxf(nrm[3][r],1e-16f))*0.125f;
      float mx = fmaxf(fmaxf(s0,s1),fmaxf(s2,s3));
      mx = fmaxf(mx, __shfl_xor(mx,1));
      mx = fmaxf(mx, __shfl_xor(mx,2));
      mx = fmaxf(mx, __shfl_xor(mx,4));
      mx = fmaxf(mx, __shfl_xor(mx,8));
      const float mnew = fmaxf(mrow[r], mx);
      float sum = __expf(s0-mnew)+__expf(s1-mnew)+__expf(s2-mnew)+__expf(s3-mnew);
      sum += __shfl_xor(sum,1);
      sum += __shfl_xor(sum,2);
      sum += __shfl_xor(sum,4);
      sum += __shfl_xor(sum,8);
      lrow[r] = lrow[r]*__expf(mrow[r]-mnew) + sum;
      mrow[r] = mnew;
    }
    __syncthreads();
  }

  float rl[4];
#pragma unroll
  for (int r=0;r<4;r++) rl[r] = 1.0f / lrow[r];

  f32x4_t oacc[4];
#pragma unroll
  for (int n=0;n<4;n++) oacc[n] = zz;

  const size_t wb = (size_t)bh * S_LEN * S_LEN;

  // ---- pass 2: weights (f32 out + bf16) + PV ----
  for (int jt = 0; jt < 32; ++jt){
    stage_tile<64>(&Ks[0][0],  Kg  + (size_t)jt*64*HDIM, HDIM, wid, lane);
    stage_tile<64>(&K2s[0][0], K2g + (size_t)jt*64*HDIM, HDIM, wid, lane);
    stage_tile<64>(&Vts[0][0], Vg + jt*64, S_LEN, wid, lane);
    __syncthreads();
    f32x4_t num[4], nrm[4];
#pragma unroll
    for (int n=0;n<4;n++){ num[n]=zz; nrm[n]=zz; }
#pragma unroll
    for (int kk=0;kk<2;kk++){
      const int ko = kk*32 + cg*8;
      bf16x8_t aq  = *(const bf16x8_t*)&Qs [wid*16 + qr][ko];
      bf16x8_t aq2 = *(const bf16x8_t*)&Q2s[wid*16 + qr][ko];
#pragma unroll
      for (int n=0;n<4;n++){
        num[n] = mfma16(aq,  *(const bf16x8_t*)&Ks [n*16 + qr][ko], num[n]);
        nrm[n] = mfma16(aq2, *(const bf16x8_t*)&K2s[n*16 + qr][ko], nrm[n]);
      }
    }
#pragma unroll
    for (int n=0;n<4;n++)
#pragma unroll
      for (int r=0;r<4;r++){
        const float s = num[n][r]*rsqrtf(fmaxf(nrm[n][r],1e-16f))*0.125f;
        const float w = __expf(s - mrow[r]) * rl[r];
        const int i = qt*64 + wid*16 + cg*4 + r;
        const int j = jt*64 + n*16 + qr;
        Wout[wb + (size_t)i*S_LEN + j] = w;
        Ws[wid][cg*4 + r][n*16 + qr] = (bf16_t)w;
      }
    // PV: oacc[n] over d-tiles; A = per-wave weight tile, B = Vt tile
#pragma unroll
    for (int kk=0;kk<2;kk++){
      const int ko = kk*32 + cg*8;
      bf16x8_t aw = *(const bf16x8_t*)&Ws[wid][qr][ko];
#pragma unroll
      for (int n=0;n<4;n++)
        oacc[n] = mfma16(aw, *(const bf16x8_t*)&Vts[n*16 + qr][ko], oacc[n]);
    }
    __syncthreads();
  }

  // epilogue: out1 (pre-W_o) in head-merged layout, split hi/lo
  const int b = bh >> 4, h = bh & 15;
#pragma unroll
  for (int n=0;n<4;n++)
#pragma unroll
    for (int r=0;r<4;r++){
      const int srow = qt*64 + wid*16 + cg*4 + r;
      const int d = n*16 + qr;
      const float v = oacc[n][r];
      const bf16_t hi = (bf16_t)v;
      const float lo = v - (float)hi;
      const size_t o = ((size_t)b*S_LEN + srow)*DMODEL + (size_t)h*HDIM + d;
      o1hi[o] = hi; o1lo[o] = (bf16_t)lo;
    }
}

// ---------------- K3: output projection, split-bf16 GEMM, f32 out ----------------
__global__ __launch_bounds__(256)
void vsa_oproj_kernel(const bf16_t* __restrict__ Ahi_g, const bf16_t* __restrict__ Alo_g,
                      const bf16_t* __restrict__ Bhi_g, const bf16_t* __restrict__ Blo_g,
                      float* __restrict__ out)
{
  __shared__ __align__(16) bf16_t Ah[128][64], Al[128][64], Bh[128][64], Bl[128][64];
  const int m0 = blockIdx.x * 128;
  const int n0 = blockIdx.y * 128;
  const int tid = threadIdx.x, lane = tid & 63, wid = tid >> 6;
  const int wr = (wid >> 1) * 64, wc = (wid & 1) * 64;

  const f32x4_t zz = {0.f,0.f,0.f,0.f};
  f32x4_t acc[4][4];
#pragma unroll
  for (int i=0;i<4;i++)
#pragma unroll
    for (int j=0;j<4;j++) acc[i][j] = zz;

  for (int kt = 0; kt < 16; ++kt){
    const int k0 = kt * 64;
    stage_tile<128>(&Ah[0][0], Ahi_g + (size_t)m0*DMODEL + k0, DMODEL, wid, lane);
    stage_tile<128>(&Al[0][0], Alo_g + (size_t)m0*DMODEL + k0, DMODEL, wid, lane);
    stage_tile<128>(&Bh[0][0], Bhi_g + (size_t)n0*DMODEL + k0, DMODEL, wid, lane);
    stage_tile<128>(&Bl[0][0], Blo_g + (size_t)n0*DMODEL + k0, DMODEL, wid, lane);
    __syncthreads();
#pragma unroll
    for (int kk = 0; kk < 2; ++kk){
      const int ko = kk*32 + (lane>>4)*8;
      bf16x8_t ah[4], al[4], bh4[4], bl4[4];
#pragma unroll
      for (int i=0;i<4;i++){
        ah[i]  = *(const bf16x8_t*)&Ah[wr + i*16 + (lane&15)][ko];
        al[i]  = *(const bf16x8_t*)&Al[wr + i*16 + (lane&15)][ko];
        bh4[i] = *(const bf16x8_t*)&Bh[wc + i*16 + (lane&15)][ko];
        bl4[i] = *(const bf16x8_t*)&Bl[wc + i*16 + (lane&15)][ko];
      }
#pragma unroll
      for (int i=0;i<4;i++)
#pragma unroll
        for (int j=0;j<4;j++){
          acc[i][j] = mfma16(ah[i], bh4[j], acc[i][j]);
          acc[i][j] = mfma16(ah[i], bl4[j], acc[i][j]);
          acc[i][j] = mfma16(al[i], bh4[j], acc[i][j]);
        }
    }
    __syncthreads();
  }

#pragma unroll
  for (int i=0;i<4;i++)
#pragma unroll
    for (int j=0;j<4;j++)
#pragma unroll
      for (int r=0;r<4;r++){
        const int m = m0 + wr + i*16 + ((lane>>4)<<2) + r;
        const int n = n0 + wc + j*16 + (lane&15);
        out[(size_t)m*DMODEL + n] = acc[i][j][r];
      }
}

extern "C" void kernel_launch(void* const* d_in, const int* in_sizes, int n_in,
                              void* d_out, int out_size, void* d_ws, size_t ws_size,
                              hipStream_t stream)
{
  const float* x  = (const float*)d_in[0];
  const float* Wq = (const float*)d_in[1];
  const float* Wk = (const float*)d_in[2];
  const float* Wv = (const float*)d_in[3];
  const float* Wo = (const float*)d_in[4];
  float* out  = (float*)d_out;
  float* attw = out + (size_t)MTOT*DMODEL;   // tuple output 1: [B,H,S,S]

  // workspace layout (bf16 elements, each slab 4194304 elts = 8 MB)
  bf16_t* ws = (bf16_t*)d_ws;
  const size_t C = 4194304;
  bf16_t* xhi  = ws;
  bf16_t* xlo  = ws + C;
  bf16_t* Whi  = ws + 2*C;   // [4][1024*1024] order q,k,v,o
  bf16_t* Wlo  = ws + 3*C;
  bf16_t* Qb   = ws + 4*C;
  bf16_t* Q2b  = ws + 5*C;
  bf16_t* Kb   = ws + 6*C;
  bf16_t* K2b  = ws + 7*C;
  bf16_t* Vtb  = ws + 8*C;
  bf16_t* o1hi = ws + 9*C;
  bf16_t* o1lo = ws + 10*C;

  const int W1 = DMODEL*DMODEL; // 1048576
  vsa_split_kernel<<<(int)(C/1024), 256, 0, stream>>>(x,  xhi, xlo, (int)(C/4));
  vsa_split_kernel<<<W1/1024, 256, 0, stream>>>(Wq, Whi + 0*(size_t)W1, Wlo + 0*(size_t)W1, W1/4);
  vsa_split_kernel<<<W1/1024, 256, 0, stream>>>(Wk, Whi + 1*(size_t)W1, Wlo + 1*(size_t)W1, W1/4);
  vsa_split_kernel<<<W1/1024, 256, 0, stream>>>(Wv, Whi + 2*(size_t)W1, Wlo + 2*(size_t)W1, W1/4);
  vsa_split_kernel<<<W1/1024, 256, 0, stream>>>(Wo, Whi + 3*(size_t)W1, Wlo + 3*(size_t)W1, W1/4);

  vsa_qkv_kernel<<<dim3(32, 8, 3), 256, 0, stream>>>(xhi, xlo, Whi, Wlo,
                                                     Qb, Q2b, Kb, K2b, Vtb);
  vsa_attn_kernel<<<dim3(32, 32), 256, 0, stream>>>(Qb, Q2b, Kb, K2b, Vtb,
                                                    attw, o1hi, o1lo);
  vsa_oproj_kernel<<<dim3(32, 8), 256, 0, stream>>>(o1hi, o1lo,
                                                    Whi + 3*(size_t)W1, Wlo + 3*(size_t)W1,
                                                    out);
}

// Round 2
// 472.130 us; speedup vs baseline: 1.1524x; 1.1524x over previous
//
#include <hip/hip_runtime.h>
#include <stdint.h>

typedef __bf16 bf16_t;
typedef __bf16 bf16x4_t __attribute__((ext_vector_type(4)));
typedef __bf16 bf16x8_t __attribute__((ext_vector_type(8)));
typedef float  f32x4_t  __attribute__((ext_vector_type(4)));

#define S_LEN 2048
#define DMODEL 1024
#define NHEAD 16
#define HDIM 64
#define MTOT 4096   // B*S

__device__ __forceinline__ f32x4_t mfma16(bf16x8_t a, bf16x8_t b, f32x4_t c){
  return __builtin_amdgcn_mfma_f32_16x16x32_bf16(a, b, c, 0, 0, 0);
}

__device__ __forceinline__ void gload_lds16(const bf16_t* g, bf16_t* l){
  __builtin_amdgcn_global_load_lds(
      (const __attribute__((address_space(1))) void*)(uintptr_t)g,
      (__attribute__((address_space(3))) void*)(uintptr_t)l,
      16, 0, 0);
}

// XOR-swizzled [ROWS][64] bf16 tile.  Logical (row, col) lives at LDS element
// row*64 + (col ^ ((row&7)<<3)).  global_load_lds writes linearly (wave base +
// lane*16B), so we pre-swizzle the per-lane GLOBAL source column instead
// (both-sides-or-neither rule): lane covers phys row lane>>3, phys col block
// lane&7  ->  logical col block (lane&7)^(lane>>3).
template<int ROWS>
__device__ __forceinline__ void stage_tile(bf16_t* lds, const bf16_t* __restrict__ g,
                                           int ldg, int wid, int lane){
  const int rl = lane >> 3;                    // row within the 8-row chunk
  const int cs = ((lane & 7) ^ rl) << 3;       // pre-swizzled source col (elems)
#pragma unroll
  for (int it = 0; it < ROWS/32; ++it){
    const int chunk = it*4 + wid;              // 8 rows per chunk, wave-uniform
    gload_lds16(g + (size_t)(chunk*8 + rl)*ldg + cs, lds + chunk*512);
  }
}

__device__ __forceinline__ bf16x8_t lds_read8(const bf16_t* t, int row, int ko){
  return *(const bf16x8_t*)&t[row*64 + (ko ^ ((row & 7) << 3))];
}

__device__ __forceinline__ bf16x8_t sq8(bf16x8_t v){
  bf16x8_t r;
#pragma unroll
  for (int i=0;i<8;i++){ float f = (float)v[i]; r[i] = (bf16_t)(f*f); }
  return r;
}

// ---------------- K0: f32 -> bf16 hi/lo split ----------------
__global__ __launch_bounds__(256)
void vsa_split_kernel(const float* __restrict__ src, bf16_t* __restrict__ hi,
                      bf16_t* __restrict__ lo, int n4){
  int i = blockIdx.x*256 + threadIdx.x;
  if (i >= n4) return;
  float4 v = ((const float4*)src)[i];
  bf16_t h0=(bf16_t)v.x, h1=(bf16_t)v.y, h2=(bf16_t)v.z, h3=(bf16_t)v.w;
  bf16x4_t hv = {h0,h1,h2,h3};
  bf16x4_t lv = {(bf16_t)(v.x-(float)h0),(bf16_t)(v.y-(float)h1),
                 (bf16_t)(v.z-(float)h2),(bf16_t)(v.w-(float)h3)};
  ((bf16x4_t*)hi)[i] = hv;
  ((bf16x4_t*)lo)[i] = lv;
}

// ---------------- K1: QKV projection, split-bf16 (3-MFMA) GEMM ----------------
__global__ __launch_bounds__(256)
void vsa_qkv_kernel(const bf16_t* __restrict__ xhi, const bf16_t* __restrict__ xlo,
                    const bf16_t* __restrict__ Whi, const bf16_t* __restrict__ Wlo,
                    bf16_t* __restrict__ Qb, bf16_t* __restrict__ Kb,
                    bf16_t* __restrict__ K2b, bf16_t* __restrict__ Vtb)
{
  __shared__ __align__(16) bf16_t Ah[128][64], Al[128][64], Bh[128][64], Bl[128][64];
  const int z  = blockIdx.z;                 // 0=Q,1=K,2=V
  const int m0 = blockIdx.x * 128;
  const int n0 = blockIdx.y * 128;
  const int tid = threadIdx.x, lane = tid & 63, wid = tid >> 6;
  const int wr = (wid >> 1) * 64, wc = (wid & 1) * 64;
  const bf16_t* Wh = Whi + (size_t)z * (DMODEL*DMODEL);
  const bf16_t* Wl = Wlo + (size_t)z * (DMODEL*DMODEL);

  const f32x4_t zz = {0.f,0.f,0.f,0.f};
  f32x4_t acc[4][4];
#pragma unroll
  for (int i=0;i<4;i++)
#pragma unroll
    for (int j=0;j<4;j++) acc[i][j] = zz;

  for (int kt = 0; kt < 16; ++kt){
    const int k0 = kt * 64;
    stage_tile<128>(&Ah[0][0], xhi + (size_t)m0*DMODEL + k0, DMODEL, wid, lane);
    stage_tile<128>(&Al[0][0], xlo + (size_t)m0*DMODEL + k0, DMODEL, wid, lane);
    stage_tile<128>(&Bh[0][0], Wh  + (size_t)n0*DMODEL + k0, DMODEL, wid, lane);
    stage_tile<128>(&Bl[0][0], Wl  + (size_t)n0*DMODEL + k0, DMODEL, wid, lane);
    __syncthreads();
#pragma unroll
    for (int kk = 0; kk < 2; ++kk){
      const int ko = kk*32 + (lane>>4)*8;
      bf16x8_t ah[4], al[4], bh4[4], bl4[4];
#pragma unroll
      for (int i=0;i<4;i++){
        const int ar = wr + i*16 + (lane&15);
        const int br = wc + i*16 + (lane&15);
        ah[i]  = lds_read8(&Ah[0][0], ar, ko);
        al[i]  = lds_read8(&Al[0][0], ar, ko);
        bh4[i] = lds_read8(&Bh[0][0], br, ko);
        bl4[i] = lds_read8(&Bl[0][0], br, ko);
      }
#pragma unroll
      for (int i=0;i<4;i++)
#pragma unroll
        for (int j=0;j<4;j++){
          acc[i][j] = mfma16(ah[i], bh4[j], acc[i][j]);
          acc[i][j] = mfma16(ah[i], bl4[j], acc[i][j]);
          acc[i][j] = mfma16(al[i], bh4[j], acc[i][j]);
        }
    }
    __syncthreads();
  }

#pragma unroll
  for (int i=0;i<4;i++)
#pragma unroll
    for (int j=0;j<4;j++)
#pragma unroll
      for (int r=0;r<4;r++){
        const int m = m0 + wr + i*16 + ((lane>>4)<<2) + r;
        const int n = n0 + wc + j*16 + (lane&15);
        const float q = acc[i][j][r];
        const int b = m >> 11, s = m & 2047, h = n >> 6, d = n & 63;
        const size_t bh_ = (size_t)b*NHEAD + h;
        if (z == 0){
          Qb[(bh_*S_LEN + s)*HDIM + d] = (bf16_t)q;
        } else if (z == 1){
          const size_t o = (bh_*S_LEN + s)*HDIM + d;
          Kb[o] = (bf16_t)q; K2b[o] = (bf16_t)(q*q);
        } else {
          Vtb[(bh_*HDIM + d)*S_LEN + s] = (bf16_t)q;   // V transposed [64][S]
        }
      }
}

// ---------------- K2: attention (two-pass exact softmax + PV) ----------------
// 1 WG = (b,h, 64-row q-tile). 4 waves; wave w owns q-rows [w*16, w*16+16).
// LDS 32 KB: Qs (reused as P tile after Q-fragment hoist), Ks, K2s, Vts.
__global__ __launch_bounds__(256)
void vsa_attn_kernel(const bf16_t* __restrict__ Qb,
                     const bf16_t* __restrict__ Kb, const bf16_t* __restrict__ K2b,
                     const bf16_t* __restrict__ Vtb,
                     float* __restrict__ Wout,
                     bf16_t* __restrict__ o1hi, bf16_t* __restrict__ o1lo)
{
  __shared__ __align__(16) bf16_t Qs[64][64], Ks[64][64], K2s[64][64], Vts[64][64];
  bf16_t* Wsf = &Qs[0][0];   // P tile aliases Qs (per-wave slices, no x-wave hazard)

  const int qt = blockIdx.x;       // 0..31
  const int bh = blockIdx.y;       // 0..31
  const int tid = threadIdx.x, lane = tid & 63, wid = tid >> 6;
  const size_t base = (size_t)bh * (S_LEN*HDIM);
  const bf16_t* Kg  = Kb  + base;
  const bf16_t* K2g = K2b + base;
  const bf16_t* Vg  = Vtb + base;   // [64][2048]

  stage_tile<64>(&Qs[0][0], Qb + base + (size_t)qt*64*HDIM, HDIM, wid, lane);
  __syncthreads();

  const int qr = lane & 15;        // fragment row index
  const int cg = lane >> 4;        // k-group; C row = cg*4 + r
  bf16x8_t aq[2], aq2[2];
#pragma unroll
  for (int kk=0;kk<2;kk++){
    aq[kk]  = lds_read8(&Qs[0][0], wid*16 + qr, kk*32 + cg*8);
    aq2[kk] = sq8(aq[kk]);
  }
  __syncthreads();

  float mrow[4], lrow[4];
#pragma unroll
  for (int r=0;r<4;r++){ mrow[r] = -1e30f; lrow[r] = 0.f; }

  const f32x4_t zz = {0.f,0.f,0.f,0.f};

  // ---- pass 1: softmax stats (m, l) ----
  for (int jt = 0; jt < 32; ++jt){
    stage_tile<64>(&Ks[0][0],  Kg  + (size_t)jt*64*HDIM, HDIM, wid, lane);
    stage_tile<64>(&K2s[0][0], K2g + (size_t)jt*64*HDIM, HDIM, wid, lane);
    __syncthreads();
    f32x4_t num[4], nrm[4];
#pragma unroll
    for (int n=0;n<4;n++){ num[n]=zz; nrm[n]=zz; }
#pragma unroll
    for (int kk=0;kk<2;kk++){
      const int ko = kk*32 + cg*8;
#pragma unroll
      for (int n=0;n<4;n++){
        num[n] = mfma16(aq[kk],  lds_read8(&Ks[0][0],  n*16 + qr, ko), num[n]);
        nrm[n] = mfma16(aq2[kk], lds_read8(&K2s[0][0], n*16 + qr, ko), nrm[n]);
      }
    }
#pragma unroll
    for (int r=0;r<4;r++){
      float s0 = num[0][r]*rsqrtf(fmaxf(nrm[0][r],1e-16f))*0.125f;
      float s1 = num[1][r]*rsqrtf(fmaxf(nrm[1][r],1e-16f))*0.125f;
      float s2 = num[2][r]*rsqrtf(fmaxf(nrm[2][r],1e-16f))*0.125f;
      float s3 = num[3][r]*rsqrtf(fmaxf(nrm[3][r],1e-16f))*0.125f;
      float mx = fmaxf(fmaxf(s0,s1),fmaxf(s2,s3));
      mx = fmaxf(mx, __shfl_xor(mx,1));
      mx = fmaxf(mx, __shfl_xor(mx,2));
      mx = fmaxf(mx, __shfl_xor(mx,4));
      mx = fmaxf(mx, __shfl_xor(mx,8));
      const float mnew = fmaxf(mrow[r], mx);
      float sum = __expf(s0-mnew)+__expf(s1-mnew)+__expf(s2-mnew)+__expf(s3-mnew);
      sum += __shfl_xor(sum,1);
      sum += __shfl_xor(sum,2);
      sum += __shfl_xor(sum,4);
      sum += __shfl_xor(sum,8);
      lrow[r] = lrow[r]*__expf(mrow[r]-mnew) + sum;
      mrow[r] = mnew;
    }
    __syncthreads();
  }

  float rl[4];
#pragma unroll
  for (int r=0;r<4;r++) rl[r] = 1.0f / lrow[r];

  f32x4_t oacc[4];
#pragma unroll
  for (int n=0;n<4;n++) oacc[n] = zz;

  const size_t wb = (size_t)bh * S_LEN * S_LEN;

  // ---- pass 2: weights (f32 out + bf16 P) + PV ----
  for (int jt = 0; jt < 32; ++jt){
    stage_tile<64>(&Ks[0][0],  Kg  + (size_t)jt*64*HDIM, HDIM, wid, lane);
    stage_tile<64>(&K2s[0][0], K2g + (size_t)jt*64*HDIM, HDIM, wid, lane);
    stage_tile<64>(&Vts[0][0], Vg + jt*64, S_LEN, wid, lane);
    __syncthreads();
    f32x4_t num[4], nrm[4];
#pragma unroll
    for (int n=0;n<4;n++){ num[n]=zz; nrm[n]=zz; }
#pragma unroll
    for (int kk=0;kk<2;kk++){
      const int ko = kk*32 + cg*8;
#pragma unroll
      for (int n=0;n<4;n++){
        num[n] = mfma16(aq[kk],  lds_read8(&Ks[0][0],  n*16 + qr, ko), num[n]);
        nrm[n] = mfma16(aq2[kk], lds_read8(&K2s[0][0], n*16 + qr, ko), nrm[n]);
      }
    }
#pragma unroll
    for (int n=0;n<4;n++)
#pragma unroll
      for (int r=0;r<4;r++){
        const float s = num[n][r]*rsqrtf(fmaxf(nrm[n][r],1e-16f))*0.125f;
        const float w = __expf(s - mrow[r]) * rl[r];
        const int i = qt*64 + wid*16 + cg*4 + r;
        const int j = jt*64 + n*16 + qr;
        Wout[wb + (size_t)i*S_LEN + j] = w;
        const int prow = wid*16 + cg*4 + r;
        Wsf[prow*64 + ((n*16 + qr) ^ (((cg*4 + r) & 7) << 3))] = (bf16_t)w;
      }
    // PV: per-wave P tile (A) x Vt tile (B)
#pragma unroll
    for (int kk=0;kk<2;kk++){
      const int ko = kk*32 + cg*8;
      bf16x8_t aw = lds_read8(Wsf, wid*16 + qr, ko);
#pragma unroll
      for (int n=0;n<4;n++)
        oacc[n] = mfma16(aw, lds_read8(&Vts[0][0], n*16 + qr, ko), oacc[n]);
    }
    __syncthreads();
  }

  // epilogue: out1 (pre-W_o) in head-merged layout, split hi/lo
  const int b = bh >> 4, h = bh & 15;
#pragma unroll
  for (int n=0;n<4;n++)
#pragma unroll
    for (int r=0;r<4;r++){
      const int srow = qt*64 + wid*16 + cg*4 + r;
      const int d = n*16 + qr;
      const float v = oacc[n][r];
      const bf16_t hi = (bf16_t)v;
      const float lo = v - (float)hi;
      const size_t o = ((size_t)b*S_LEN + srow)*DMODEL + (size_t)h*HDIM + d;
      o1hi[o] = hi; o1lo[o] = (bf16_t)lo;
    }
}

// ---------------- K3: output projection, split-bf16 GEMM, f32 out ----------------
__global__ __launch_bounds__(256)
void vsa_oproj_kernel(const bf16_t* __restrict__ Ahi_g, const bf16_t* __restrict__ Alo_g,
                      const bf16_t* __restrict__ Bhi_g, const bf16_t* __restrict__ Blo_g,
                      float* __restrict__ out)
{
  __shared__ __align__(16) bf16_t Ah[128][64], Al[128][64], Bh[128][64], Bl[128][64];
  const int m0 = blockIdx.x * 128;
  const int n0 = blockIdx.y * 128;
  const int tid = threadIdx.x, lane = tid & 63, wid = tid >> 6;
  const int wr = (wid >> 1) * 64, wc = (wid & 1) * 64;

  const f32x4_t zz = {0.f,0.f,0.f,0.f};
  f32x4_t acc[4][4];
#pragma unroll
  for (int i=0;i<4;i++)
#pragma unroll
    for (int j=0;j<4;j++) acc[i][j] = zz;

  for (int kt = 0; kt < 16; ++kt){
    const int k0 = kt * 64;
    stage_tile<128>(&Ah[0][0], Ahi_g + (size_t)m0*DMODEL + k0, DMODEL, wid, lane);
    stage_tile<128>(&Al[0][0], Alo_g + (size_t)m0*DMODEL + k0, DMODEL, wid, lane);
    stage_tile<128>(&Bh[0][0], Bhi_g + (size_t)n0*DMODEL + k0, DMODEL, wid, lane);
    stage_tile<128>(&Bl[0][0], Blo_g + (size_t)n0*DMODEL + k0, DMODEL, wid, lane);
    __syncthreads();
#pragma unroll
    for (int kk = 0; kk < 2; ++kk){
      const int ko = kk*32 + (lane>>4)*8;
      bf16x8_t ah[4], al[4], bh4[4], bl4[4];
#pragma unroll
      for (int i=0;i<4;i++){
        const int ar = wr + i*16 + (lane&15);
        const int br = wc + i*16 + (lane&15);
        ah[i]  = lds_read8(&Ah[0][0], ar, ko);
        al[i]  = lds_read8(&Al[0][0], ar, ko);
        bh4[i] = lds_read8(&Bh[0][0], br, ko);
        bl4[i] = lds_read8(&Bl[0][0], br, ko);
      }
#pragma unroll
      for (int i=0;i<4;i++)
#pragma unroll
        for (int j=0;j<4;j++){
          acc[i][j] = mfma16(ah[i], bh4[j], acc[i][j]);
          acc[i][j] = mfma16(ah[i], bl4[j], acc[i][j]);
          acc[i][j] = mfma16(al[i], bh4[j], acc[i][j]);
        }
    }
    __syncthreads();
  }

#pragma unroll
  for (int i=0;i<4;i++)
#pragma unroll
    for (int j=0;j<4;j++)
#pragma unroll
      for (int r=0;r<4;r++){
        const int m = m0 + wr + i*16 + ((lane>>4)<<2) + r;
        const int n = n0 + wc + j*16 + (lane&15);
        out[(size_t)m*DMODEL + n] = acc[i][j][r];
      }
}

extern "C" void kernel_launch(void* const* d_in, const int* in_sizes, int n_in,
                              void* d_out, int out_size, void* d_ws, size_t ws_size,
                              hipStream_t stream)
{
  const float* x  = (const float*)d_in[0];
  const float* Wq = (const float*)d_in[1];
  const float* Wk = (const float*)d_in[2];
  const float* Wv = (const float*)d_in[3];
  const float* Wo = (const float*)d_in[4];
  float* out  = (float*)d_out;
  float* attw = out + (size_t)MTOT*DMODEL;   // tuple output 1: [B,H,S,S]

  // workspace layout (bf16 elements, each slab 4194304 elts = 8 MB)
  bf16_t* ws = (bf16_t*)d_ws;
  const size_t C = 4194304;
  bf16_t* xhi  = ws;
  bf16_t* xlo  = ws + C;
  bf16_t* Whi  = ws + 2*C;   // [4][1024*1024] order q,k,v,o
  bf16_t* Wlo  = ws + 3*C;
  bf16_t* Qb   = ws + 4*C;
  bf16_t* Kb   = ws + 5*C;
  bf16_t* K2b  = ws + 6*C;
  bf16_t* Vtb  = ws + 7*C;
  bf16_t* o1hi = ws + 8*C;
  bf16_t* o1lo = ws + 9*C;

  const int W1 = DMODEL*DMODEL; // 1048576
  vsa_split_kernel<<<(int)(C/1024), 256, 0, stream>>>(x,  xhi, xlo, (int)(C/4));
  vsa_split_kernel<<<W1/1024, 256, 0, stream>>>(Wq, Whi + 0*(size_t)W1, Wlo + 0*(size_t)W1, W1/4);
  vsa_split_kernel<<<W1/1024, 256, 0, stream>>>(Wk, Whi + 1*(size_t)W1, Wlo + 1*(size_t)W1, W1/4);
  vsa_split_kernel<<<W1/1024, 256, 0, stream>>>(Wv, Whi + 2*(size_t)W1, Wlo + 2*(size_t)W1, W1/4);
  vsa_split_kernel<<<W1/1024, 256, 0, stream>>>(Wo, Whi + 3*(size_t)W1, Wlo + 3*(size_t)W1, W1/4);

  vsa_qkv_kernel<<<dim3(32, 8, 3), 256, 0, stream>>>(xhi, xlo, Whi, Wlo,
                                                     Qb, Kb, K2b, Vtb);
  vsa_attn_kernel<<<dim3(32, 32), 256, 0, stream>>>(Qb, Kb, K2b, Vtb,
                                                    attw, o1hi, o1lo);
  vsa_oproj_kernel<<<dim3(32, 8), 256, 0, stream>>>(o1hi, o1lo,
                                                    Whi + 3*(size_t)W1, Wlo + 3*(size_t)W1,
                                                    out);
}

// Round 3
// 415.944 us; speedup vs baseline: 1.3080x; 1.1351x over previous
//
#include <hip/hip_runtime.h>
#include <stdint.h>

typedef __bf16 bf16_t;
typedef __bf16 bf16x4_t __attribute__((ext_vector_type(4)));
typedef __bf16 bf16x8_t __attribute__((ext_vector_type(8)));
typedef float  f32x4_t  __attribute__((ext_vector_type(4)));

#define S_LEN 2048
#define DMODEL 1024
#define NHEAD 16
#define HDIM 64
#define MTOT 4096   // B*S

__device__ __forceinline__ f32x4_t mfma16(bf16x8_t a, bf16x8_t b, f32x4_t c){
  return __builtin_amdgcn_mfma_f32_16x16x32_bf16(a, b, c, 0, 0, 0);
}

__device__ __forceinline__ void gload_lds16(const bf16_t* g, bf16_t* l){
  __builtin_amdgcn_global_load_lds(
      (const __attribute__((address_space(1))) void*)(uintptr_t)g,
      (__attribute__((address_space(3))) void*)(uintptr_t)l,
      16, 0, 0);
}

// XOR-swizzled [ROWS][64] bf16 tile.  Logical (row, col) lives at LDS element
// row*64 + (col ^ ((row&7)<<3)).  global_load_lds writes linearly, so the
// per-lane GLOBAL source column is pre-swizzled instead (both-sides rule).
template<int ROWS>
__device__ __forceinline__ void stage_tile(bf16_t* lds, const bf16_t* __restrict__ g,
                                           int ldg, int wid, int lane){
  const int rl = lane >> 3;                    // row within the 8-row chunk
  const int cs = ((lane & 7) ^ rl) << 3;       // pre-swizzled source col (elems)
#pragma unroll
  for (int it = 0; it < ROWS/32; ++it){
    const int chunk = it*4 + wid;              // 8 rows per chunk, wave-uniform
    gload_lds16(g + (size_t)(chunk*8 + rl)*ldg + cs, lds + chunk*512);
  }
}

__device__ __forceinline__ bf16x8_t lds_read8(const bf16_t* t, int row, int ko){
  return *(const bf16x8_t*)&t[row*64 + (ko ^ ((row & 7) << 3))];
}

__device__ __forceinline__ bf16x8_t sq8(bf16x8_t v){
  bf16x8_t r;
#pragma unroll
  for (int i=0;i<8;i++){ float f = (float)v[i]; r[i] = (bf16_t)(f*f); }
  return r;
}

// ---------------- K0: f32 -> bf16 hi/lo split ----------------
__global__ __launch_bounds__(256)
void vsa_split_kernel(const float* __restrict__ src, bf16_t* __restrict__ hi,
                      bf16_t* __restrict__ lo, int n4){
  int i = blockIdx.x*256 + threadIdx.x;
  if (i >= n4) return;
  float4 v = ((const float4*)src)[i];
  bf16_t h0=(bf16_t)v.x, h1=(bf16_t)v.y, h2=(bf16_t)v.z, h3=(bf16_t)v.w;
  bf16x4_t hv = {h0,h1,h2,h3};
  bf16x4_t lv = {(bf16_t)(v.x-(float)h0),(bf16_t)(v.y-(float)h1),
                 (bf16_t)(v.z-(float)h2),(bf16_t)(v.w-(float)h3)};
  ((bf16x4_t*)hi)[i] = hv;
  ((bf16x4_t*)lo)[i] = lv;
}

// ---------------- K1: QKV projection, split-bf16 (3-MFMA) GEMM ----------------
__global__ __launch_bounds__(256)
void vsa_qkv_kernel(const bf16_t* __restrict__ xhi, const bf16_t* __restrict__ xlo,
                    const bf16_t* __restrict__ Whi, const bf16_t* __restrict__ Wlo,
                    bf16_t* __restrict__ Qb, bf16_t* __restrict__ Kb,
                    bf16_t* __restrict__ K2b, bf16_t* __restrict__ Vtb)
{
  __shared__ __align__(16) bf16_t Ah[128][64], Al[128][64], Bh[128][64], Bl[128][64];
  const int z  = blockIdx.z;                 // 0=Q,1=K,2=V
  const int m0 = blockIdx.x * 128;
  const int n0 = blockIdx.y * 128;
  const int tid = threadIdx.x, lane = tid & 63, wid = tid >> 6;
  const int wr = (wid >> 1) * 64, wc = (wid & 1) * 64;
  const bf16_t* Wh = Whi + (size_t)z * (DMODEL*DMODEL);
  const bf16_t* Wl = Wlo + (size_t)z * (DMODEL*DMODEL);

  const f32x4_t zz = {0.f,0.f,0.f,0.f};
  f32x4_t acc[4][4];
#pragma unroll
  for (int i=0;i<4;i++)
#pragma unroll
    for (int j=0;j<4;j++) acc[i][j] = zz;

  for (int kt = 0; kt < 16; ++kt){
    const int k0 = kt * 64;
    stage_tile<128>(&Ah[0][0], xhi + (size_t)m0*DMODEL + k0, DMODEL, wid, lane);
    stage_tile<128>(&Al[0][0], xlo + (size_t)m0*DMODEL + k0, DMODEL, wid, lane);
    stage_tile<128>(&Bh[0][0], Wh  + (size_t)n0*DMODEL + k0, DMODEL, wid, lane);
    stage_tile<128>(&Bl[0][0], Wl  + (size_t)n0*DMODEL + k0, DMODEL, wid, lane);
    __syncthreads();
#pragma unroll
    for (int kk = 0; kk < 2; ++kk){
      const int ko = kk*32 + (lane>>4)*8;
      bf16x8_t ah[4], al[4], bh4[4], bl4[4];
#pragma unroll
      for (int i=0;i<4;i++){
        const int ar = wr + i*16 + (lane&15);
        const int br = wc + i*16 + (lane&15);
        ah[i]  = lds_read8(&Ah[0][0], ar, ko);
        al[i]  = lds_read8(&Al[0][0], ar, ko);
        bh4[i] = lds_read8(&Bh[0][0], br, ko);
        bl4[i] = lds_read8(&Bl[0][0], br, ko);
      }
#pragma unroll
      for (int i=0;i<4;i++)
#pragma unroll
        for (int j=0;j<4;j++){
          acc[i][j] = mfma16(ah[i], bh4[j], acc[i][j]);
          acc[i][j] = mfma16(ah[i], bl4[j], acc[i][j]);
          acc[i][j] = mfma16(al[i], bh4[j], acc[i][j]);
        }
    }
    __syncthreads();
  }

#pragma unroll
  for (int i=0;i<4;i++)
#pragma unroll
    for (int j=0;j<4;j++)
#pragma unroll
      for (int r=0;r<4;r++){
        const int m = m0 + wr + i*16 + ((lane>>4)<<2) + r;
        const int n = n0 + wc + j*16 + (lane&15);
        const float q = acc[i][j][r];
        const int b = m >> 11, s = m & 2047, h = n >> 6, d = n & 63;
        const size_t bh_ = (size_t)b*NHEAD + h;
        if (z == 0){
          Qb[(bh_*S_LEN + s)*HDIM + d] = (bf16_t)q;
        } else if (z == 1){
          const size_t o = (bh_*S_LEN + s)*HDIM + d;
          Kb[o] = (bf16_t)q; K2b[o] = (bf16_t)(q*q);
        } else {
          Vtb[(bh_*HDIM + d)*S_LEN + s] = (bf16_t)q;   // V transposed [64][S]
        }
      }
}

// ---------------- K2: attention, two-pass, no-max (bounded scores), ----------
// 2-phase prefetch pipeline.  1 WG = (b,h, 64-row q-tile), 4 waves.
// LDS 40KB: K[2], K2[2] double-buffered; P tile; V + Q direct from global.
__global__ __launch_bounds__(256, 4)
void vsa_attn_kernel(const bf16_t* __restrict__ Qb,
                     const bf16_t* __restrict__ Kb, const bf16_t* __restrict__ K2b,
                     const bf16_t* __restrict__ Vtb,
                     float* __restrict__ Wout,
                     bf16_t* __restrict__ o1hi, bf16_t* __restrict__ o1lo)
{
  __shared__ __align__(16) bf16_t Ks[2][64][64], K2s[2][64][64], Ps[4][16][64];

  const int qt = blockIdx.x;       // 0..31
  const int bh = blockIdx.y;       // 0..31
  const int tid = threadIdx.x, lane = tid & 63, wid = tid >> 6;
  const size_t base = (size_t)bh * (S_LEN*HDIM);
  const bf16_t* Kg  = Kb  + base;
  const bf16_t* K2g = K2b + base;
  const bf16_t* Vg  = Vtb + base;   // [64][2048]

  const int qr = lane & 15;        // fragment row index
  const int cg = lane >> 4;        // k-group; C row = cg*4 + r

  // Q fragments direct from global (row is 128B-aligned, 16B loads)
  const bf16_t* qrow = Qb + base + (size_t)(qt*64 + wid*16 + qr)*HDIM;
  bf16x8_t aq[2], aq2[2];
  aq[0] = *(const bf16x8_t*)(qrow + cg*8);
  aq[1] = *(const bf16x8_t*)(qrow + 32 + cg*8);
  aq2[0] = sq8(aq[0]);
  aq2[1] = sq8(aq[1]);

  const f32x4_t zz = {0.f,0.f,0.f,0.f};
  float lpart[4] = {0.f,0.f,0.f,0.f};

  // ---- pass 1: row sums l = sum_j exp(s) (scores bounded by ~1: no max) ----
  stage_tile<64>(&Ks[0][0][0],  Kg,  HDIM, wid, lane);
  stage_tile<64>(&K2s[0][0][0], K2g, HDIM, wid, lane);
  for (int jt = 0; jt < 32; ++jt){
    __syncthreads();               // drains my stage loads; all waves synced
    if (jt + 1 < 32){
      stage_tile<64>(&Ks[(jt+1)&1][0][0],  Kg  + (size_t)(jt+1)*64*HDIM, HDIM, wid, lane);
      stage_tile<64>(&K2s[(jt+1)&1][0][0], K2g + (size_t)(jt+1)*64*HDIM, HDIM, wid, lane);
    }
    const bf16_t* kb  = &Ks [jt&1][0][0];
    const bf16_t* k2b = &K2s[jt&1][0][0];
    f32x4_t num[4], nrm[4];
#pragma unroll
    for (int n=0;n<4;n++){ num[n]=zz; nrm[n]=zz; }
#pragma unroll
    for (int kk=0;kk<2;kk++){
      const int ko = kk*32 + cg*8;
#pragma unroll
      for (int n=0;n<4;n++){
        num[n] = mfma16(aq[kk],  lds_read8(kb,  n*16 + qr, ko), num[n]);
        nrm[n] = mfma16(aq2[kk], lds_read8(k2b, n*16 + qr, ko), nrm[n]);
      }
    }
#pragma unroll
    for (int n=0;n<4;n++)
#pragma unroll
      for (int r=0;r<4;r++){
        const float s = num[n][r]*rsqrtf(fmaxf(nrm[n][r],1e-16f))*0.125f;
        lpart[r] += __expf(s);
      }
  }

  // deferred cross-lane row-sum reduce (16 lanes share a row group)
  float rl[4];
#pragma unroll
  for (int r=0;r<4;r++){
    float l = lpart[r];
    l += __shfl_xor(l,1); l += __shfl_xor(l,2);
    l += __shfl_xor(l,4); l += __shfl_xor(l,8);
    rl[r] = 1.0f / l;
  }

  f32x4_t oacc[4];
#pragma unroll
  for (int n=0;n<4;n++) oacc[n] = zz;

  const size_t wb = (size_t)bh * S_LEN * S_LEN;

  // ---- pass 2: weights (f32 out + bf16 P) + PV ----
  stage_tile<64>(&Ks[0][0][0],  Kg,  HDIM, wid, lane);
  stage_tile<64>(&K2s[0][0][0], K2g, HDIM, wid, lane);
  for (int jt = 0; jt < 32; ++jt){
    __syncthreads();
    if (jt + 1 < 32){
      stage_tile<64>(&Ks[(jt+1)&1][0][0],  Kg  + (size_t)(jt+1)*64*HDIM, HDIM, wid, lane);
      stage_tile<64>(&K2s[(jt+1)&1][0][0], K2g + (size_t)(jt+1)*64*HDIM, HDIM, wid, lane);
    }
    // V fragments for this tile, direct from global (issued early, used late)
    bf16x8_t vf0[4], vf1[4];
#pragma unroll
    for (int n=0;n<4;n++){
      const bf16_t* vrow = Vg + (size_t)(n*16 + qr)*S_LEN + jt*64;
      vf0[n] = *(const bf16x8_t*)(vrow + cg*8);
      vf1[n] = *(const bf16x8_t*)(vrow + 32 + cg*8);
    }
    const bf16_t* kb  = &Ks [jt&1][0][0];
    const bf16_t* k2b = &K2s[jt&1][0][0];
    f32x4_t num[4], nrm[4];
#pragma unroll
    for (int n=0;n<4;n++){ num[n]=zz; nrm[n]=zz; }
#pragma unroll
    for (int kk=0;kk<2;kk++){
      const int ko = kk*32 + cg*8;
#pragma unroll
      for (int n=0;n<4;n++){
        num[n] = mfma16(aq[kk],  lds_read8(kb,  n*16 + qr, ko), num[n]);
        nrm[n] = mfma16(aq2[kk], lds_read8(k2b, n*16 + qr, ko), nrm[n]);
      }
    }
#pragma unroll
    for (int n=0;n<4;n++)
#pragma unroll
      for (int r=0;r<4;r++){
        const float s = num[n][r]*rsqrtf(fmaxf(nrm[n][r],1e-16f))*0.125f;
        const float w = __expf(s) * rl[r];
        const int i = qt*64 + wid*16 + cg*4 + r;
        const int j = jt*64 + n*16 + qr;
        Wout[wb + (size_t)i*S_LEN + j] = w;
        const int prow = cg*4 + r;
        Ps[wid][prow][(n*16 + qr) ^ ((prow & 7) << 3)] = (bf16_t)w;
      }
    // PV: per-wave P tile (A) x V fragments (B, in registers)
#pragma unroll
    for (int kk=0;kk<2;kk++){
      const int ko = kk*32 + cg*8;
      bf16x8_t aw = *(const bf16x8_t*)&Ps[wid][qr][ko ^ ((qr & 7) << 3)];
#pragma unroll
      for (int n=0;n<4;n++)
        oacc[n] = mfma16(aw, (kk==0 ? vf0[n] : vf1[n]), oacc[n]);
    }
  }

  // epilogue: out1 (pre-W_o) in head-merged layout, split hi/lo
  const int b = bh >> 4, h = bh & 15;
#pragma unroll
  for (int n=0;n<4;n++)
#pragma unroll
    for (int r=0;r<4;r++){
      const int srow = qt*64 + wid*16 + cg*4 + r;
      const int d = n*16 + qr;
      const float v = oacc[n][r];
      const bf16_t hi = (bf16_t)v;
      const float lo = v - (float)hi;
      const size_t o = ((size_t)b*S_LEN + srow)*DMODEL + (size_t)h*HDIM + d;
      o1hi[o] = hi; o1lo[o] = (bf16_t)lo;
    }
}

// ---------------- K3: output projection, split-bf16 GEMM, f32 out ----------------
__global__ __launch_bounds__(256)
void vsa_oproj_kernel(const bf16_t* __restrict__ Ahi_g, const bf16_t* __restrict__ Alo_g,
                      const bf16_t* __restrict__ Bhi_g, const bf16_t* __restrict__ Blo_g,
                      float* __restrict__ out)
{
  __shared__ __align__(16) bf16_t Ah[128][64], Al[128][64], Bh[128][64], Bl[128][64];
  const int m0 = blockIdx.x * 128;
  const int n0 = blockIdx.y * 128;
  const int tid = threadIdx.x, lane = tid & 63, wid = tid >> 6;
  const int wr = (wid >> 1) * 64, wc = (wid & 1) * 64;

  const f32x4_t zz = {0.f,0.f,0.f,0.f};
  f32x4_t acc[4][4];
#pragma unroll
  for (int i=0;i<4;i++)
#pragma unroll
    for (int j=0;j<4;j++) acc[i][j] = zz;

  for (int kt = 0; kt < 16; ++kt){
    const int k0 = kt * 64;
    stage_tile<128>(&Ah[0][0], Ahi_g + (size_t)m0*DMODEL + k0, DMODEL, wid, lane);
    stage_tile<128>(&Al[0][0], Alo_g + (size_t)m0*DMODEL + k0, DMODEL, wid, lane);
    stage_tile<128>(&Bh[0][0], Bhi_g + (size_t)n0*DMODEL + k0, DMODEL, wid, lane);
    stage_tile<128>(&Bl[0][0], Blo_g + (size_t)n0*DMODEL + k0, DMODEL, wid, lane);
    __syncthreads();
#pragma unroll
    for (int kk = 0; kk < 2; ++kk){
      const int ko = kk*32 + (lane>>4)*8;
      bf16x8_t ah[4], al[4], bh4[4], bl4[4];
#pragma unroll
      for (int i=0;i<4;i++){
        const int ar = wr + i*16 + (lane&15);
        const int br = wc + i*16 + (lane&15);
        ah[i]  = lds_read8(&Ah[0][0], ar, ko);
        al[i]  = lds_read8(&Al[0][0], ar, ko);
        bh4[i] = lds_read8(&Bh[0][0], br, ko);
        bl4[i] = lds_read8(&Bl[0][0], br, ko);
      }
#pragma unroll
      for (int i=0;i<4;i++)
#pragma unroll
        for (int j=0;j<4;j++){
          acc[i][j] = mfma16(ah[i], bh4[j], acc[i][j]);
          acc[i][j] = mfma16(ah[i], bl4[j], acc[i][j]);
          acc[i][j] = mfma16(al[i], bh4[j], acc[i][j]);
        }
    }
    __syncthreads();
  }

#pragma unroll
  for (int i=0;i<4;i++)
#pragma unroll
    for (int j=0;j<4;j++)
#pragma unroll
      for (int r=0;r<4;r++){
        const int m = m0 + wr + i*16 + ((lane>>4)<<2) + r;
        const int n = n0 + wc + j*16 + (lane&15);
        out[(size_t)m*DMODEL + n] = acc[i][j][r];
      }
}

extern "C" void kernel_launch(void* const* d_in, const int* in_sizes, int n_in,
                              void* d_out, int out_size, void* d_ws, size_t ws_size,
                              hipStream_t stream)
{
  const float* x  = (const float*)d_in[0];
  const float* Wq = (const float*)d_in[1];
  const float* Wk = (const float*)d_in[2];
  const float* Wv = (const float*)d_in[3];
  const float* Wo = (const float*)d_in[4];
  float* out  = (float*)d_out;
  float* attw = out + (size_t)MTOT*DMODEL;   // tuple output 1: [B,H,S,S]

  // workspace layout (bf16 elements, each slab 4194304 elts = 8 MB)
  bf16_t* ws = (bf16_t*)d_ws;
  const size_t C = 4194304;
  bf16_t* xhi  = ws;
  bf16_t* xlo  = ws + C;
  bf16_t* Whi  = ws + 2*C;   // [4][1024*1024] order q,k,v,o
  bf16_t* Wlo  = ws + 3*C;
  bf16_t* Qb   = ws + 4*C;
  bf16_t* Kb   = ws + 5*C;
  bf16_t* K2b  = ws + 6*C;
  bf16_t* Vtb  = ws + 7*C;
  bf16_t* o1hi = ws + 8*C;
  bf16_t* o1lo = ws + 9*C;

  const int W1 = DMODEL*DMODEL; // 1048576
  vsa_split_kernel<<<(int)(C/1024), 256, 0, stream>>>(x,  xhi, xlo, (int)(C/4));
  vsa_split_kernel<<<W1/1024, 256, 0, stream>>>(Wq, Whi + 0*(size_t)W1, Wlo + 0*(size_t)W1, W1/4);
  vsa_split_kernel<<<W1/1024, 256, 0, stream>>>(Wk, Whi + 1*(size_t)W1, Wlo + 1*(size_t)W1, W1/4);
  vsa_split_kernel<<<W1/1024, 256, 0, stream>>>(Wv, Whi + 2*(size_t)W1, Wlo + 2*(size_t)W1, W1/4);
  vsa_split_kernel<<<W1/1024, 256, 0, stream>>>(Wo, Whi + 3*(size_t)W1, Wlo + 3*(size_t)W1, W1/4);

  vsa_qkv_kernel<<<dim3(32, 8, 3), 256, 0, stream>>>(xhi, xlo, Whi, Wlo,
                                                     Qb, Kb, K2b, Vtb);
  vsa_attn_kernel<<<dim3(32, 32), 256, 0, stream>>>(Qb, Kb, K2b, Vtb,
                                                    attw, o1hi, o1lo);
  vsa_oproj_kernel<<<dim3(32, 8), 256, 0, stream>>>(o1hi, o1lo,
                                                    Whi + 3*(size_t)W1, Wlo + 3*(size_t)W1,
                                                    out);
}

// Round 5
// 394.110 us; speedup vs baseline: 1.3805x; 1.0554x over previous
//
#include <hip/hip_runtime.h>
#include <stdint.h>

typedef __bf16 bf16_t;
typedef __bf16 bf16x4_t __attribute__((ext_vector_type(4)));
typedef __bf16 bf16x8_t __attribute__((ext_vector_type(8)));
typedef float  f32x4_t  __attribute__((ext_vector_type(4)));

#define S_LEN 2048
#define DMODEL 1024
#define NHEAD 16
#define HDIM 64
#define MTOT 4096   // B*S
#define NT 32       // K/V tiles of 64
#define WBLK 5888   // per-wave LDS block, bf16 elems: K 2048 | K2 2048 | V 1024 | P 768

__device__ __forceinline__ f32x4_t mfma16(bf16x8_t a, bf16x8_t b, f32x4_t c){
  return __builtin_amdgcn_mfma_f32_16x16x32_bf16(a, b, c, 0, 0, 0);
}

__device__ __forceinline__ void gload_lds16(const bf16_t* g, bf16_t* l){
  __builtin_amdgcn_global_load_lds(
      (const __attribute__((address_space(1))) void*)(uintptr_t)g,
      (__attribute__((address_space(3))) void*)(uintptr_t)l,
      16, 0, 0);
}

// ---- XOR-swizzled [ROWS][64] staging (linear LDS dest, pre-swizzled source) ----
template<int ROWS>
__device__ __forceinline__ void stage_tile(bf16_t* lds, const bf16_t* __restrict__ g,
                                           int ldg, int wid, int lane){
  const int rl = lane >> 3;
  const int cs = ((lane & 7) ^ rl) << 3;
#pragma unroll
  for (int it = 0; it < ROWS/32; ++it){
    const int chunk = it*4 + wid;
    gload_lds16(g + (size_t)(chunk*8 + rl)*ldg + cs, lds + chunk*512);
  }
}

// wave-level [16][64] slice (2 gload_lds), same swizzle
__device__ __forceinline__ void stage_slice16(bf16_t* lds, const bf16_t* __restrict__ g,
                                              int lane){
  const int rl = lane >> 3;
  const int cs = ((lane & 7) ^ rl) << 3;
#pragma unroll
  for (int c = 0; c < 2; ++c)
    gload_lds16(g + (size_t)(c*8 + rl)*HDIM + cs, lds + c*512);
}

// wave-level V slice [64 d][16 j] from Vblk tile [64 d][64 j] (linear, no swizzle)
// lane l writes LDS elems c*512 + l*8 = (d = c*32 + l/2) * 16 + (l&1)*8
__device__ __forceinline__ void stage_v(bf16_t* lds, const bf16_t* __restrict__ g,
                                        int lane){
#pragma unroll
  for (int c = 0; c < 2; ++c)
    gload_lds16(g + (size_t)(c*32 + (lane>>1))*64 + (lane&1)*8, lds + c*512);
}

__device__ __forceinline__ bf16x8_t lds_read8(const bf16_t* t, int row, int ko){
  return *(const bf16x8_t*)&t[row*64 + (ko ^ ((row & 7) << 3))];
}

// ---------------- K0: f32 -> bf16 hi/lo split ----------------
__global__ __launch_bounds__(256)
void vsa_split_kernel(const float* __restrict__ src, bf16_t* __restrict__ hi,
                      bf16_t* __restrict__ lo, int n4){
  int i = blockIdx.x*256 + threadIdx.x;
  if (i >= n4) return;
  float4 v = ((const float4*)src)[i];
  bf16_t h0=(bf16_t)v.x, h1=(bf16_t)v.y, h2=(bf16_t)v.z, h3=(bf16_t)v.w;
  bf16x4_t hv = {h0,h1,h2,h3};
  bf16x4_t lv = {(bf16_t)(v.x-(float)h0),(bf16_t)(v.y-(float)h1),
                 (bf16_t)(v.z-(float)h2),(bf16_t)(v.w-(float)h3)};
  ((bf16x4_t*)hi)[i] = hv;
  ((bf16x4_t*)lo)[i] = lv;
}

// ---------------- K1: QKV projection, split-bf16 (3-MFMA) GEMM ----------------
__global__ __launch_bounds__(256)
void vsa_qkv_kernel(const bf16_t* __restrict__ xhi, const bf16_t* __restrict__ xlo,
                    const bf16_t* __restrict__ Whi, const bf16_t* __restrict__ Wlo,
                    bf16_t* __restrict__ Qb, bf16_t* __restrict__ Kb,
                    bf16_t* __restrict__ K2b, bf16_t* __restrict__ Vblk)
{
  __shared__ __align__(16) bf16_t Ah[128][64], Al[128][64], Bh[128][64], Bl[128][64];
  const int z  = blockIdx.z;                 // 0=Q,1=K,2=V
  const int m0 = blockIdx.x * 128;
  const int n0 = blockIdx.y * 128;
  const int tid = threadIdx.x, lane = tid & 63, wid = tid >> 6;
  const int wr = (wid >> 1) * 64, wc = (wid & 1) * 64;
  const bf16_t* Wh = Whi + (size_t)z * (DMODEL*DMODEL);
  const bf16_t* Wl = Wlo + (size_t)z * (DMODEL*DMODEL);

  const f32x4_t zz = {0.f,0.f,0.f,0.f};
  f32x4_t acc[4][4];
#pragma unroll
  for (int i=0;i<4;i++)
#pragma unroll
    for (int j=0;j<4;j++) acc[i][j] = zz;

  for (int kt = 0; kt < 16; ++kt){
    const int k0 = kt * 64;
    stage_tile<128>(&Ah[0][0], xhi + (size_t)m0*DMODEL + k0, DMODEL, wid, lane);
    stage_tile<128>(&Al[0][0], xlo + (size_t)m0*DMODEL + k0, DMODEL, wid, lane);
    stage_tile<128>(&Bh[0][0], Wh  + (size_t)n0*DMODEL + k0, DMODEL, wid, lane);
    stage_tile<128>(&Bl[0][0], Wl  + (size_t)n0*DMODEL + k0, DMODEL, wid, lane);
    __syncthreads();
#pragma unroll
    for (int kk = 0; kk < 2; ++kk){
      const int ko = kk*32 + (lane>>4)*8;
      bf16x8_t ah[4], al[4], bh4[4], bl4[4];
#pragma unroll
      for (int i=0;i<4;i++){
        const int ar = wr + i*16 + (lane&15);
        const int br = wc + i*16 + (lane&15);
        ah[i]  = lds_read8(&Ah[0][0], ar, ko);
        al[i]  = lds_read8(&Al[0][0], ar, ko);
        bh4[i] = lds_read8(&Bh[0][0], br, ko);
        bl4[i] = lds_read8(&Bl[0][0], br, ko);
      }
#pragma unroll
      for (int i=0;i<4;i++)
#pragma unroll
        for (int j=0;j<4;j++){
          acc[i][j] = mfma16(ah[i], bh4[j], acc[i][j]);
          acc[i][j] = mfma16(ah[i], bl4[j], acc[i][j]);
          acc[i][j] = mfma16(al[i], bh4[j], acc[i][j]);
        }
    }
    __syncthreads();
  }

#pragma unroll
  for (int i=0;i<4;i++)
#pragma unroll
    for (int j=0;j<4;j++)
#pragma unroll
      for (int r=0;r<4;r++){
        const int m = m0 + wr + i*16 + ((lane>>4)<<2) + r;
        const int n = n0 + wc + j*16 + (lane&15);
        const float q = acc[i][j][r];
        const int b = m >> 11, s = m & 2047, h = n >> 6, d = n & 63;
        const size_t bh_ = (size_t)b*NHEAD + h;
        if (z == 0){
          Qb[(bh_*S_LEN + s)*HDIM + d] = (bf16_t)q;
        } else if (z == 1){
          const size_t o = (bh_*S_LEN + s)*HDIM + d;
          Kb[o] = (bf16_t)q; K2b[o] = (bf16_t)(q*q);
        } else {
          // V block-transposed: [bh][s/64][64 d][64 j]
          Vblk[bh_*(size_t)(S_LEN*HDIM) + (size_t)(s>>6)*4096 + d*64 + (s&63)] = (bf16_t)q;
        }
      }
}

// ---------------- K2: attention, barrier-free wave-owned j-slices ----------
// Grid 2048 = (qt 0..63) x (bh 0..31), bh-major XCD swizzle.
// WG = 32 q-rows, 4 waves; wave w owns j-slice [jt*64 + w*16, +16).
// No __syncthreads in the loops: per-wave global_load_lds + counted vmcnt.
// PV uses K=32 MFMA with zero-padded A on lanes cg>=2 (true K=16).
__global__ __launch_bounds__(256, 3)
void vsa_attn_kernel(const bf16_t* __restrict__ Qb,
                     const bf16_t* __restrict__ Kb, const bf16_t* __restrict__ K2b,
                     const bf16_t* __restrict__ Vblk,
                     float* __restrict__ Wout,
                     bf16_t* __restrict__ o1hi, bf16_t* __restrict__ o1lo)
{
  __shared__ __align__(16) bf16_t smem[4*WBLK];
  __shared__ float lred[4][2][16];

  const int lin = blockIdx.x;               // 0..2047
  const int xcd = lin & 7;
  const int idx = lin >> 3;                 // 0..255
  const int qt  = idx & 63;                 // 64 q-tiles of 32 rows
  const int bh  = xcd + 8*(idx >> 6);       // 4 heads per XCD -> K/V L2-resident
  const int lane = threadIdx.x & 63, w = (int)(threadIdx.x >> 6);
  const int qr = lane & 15, cg = lane >> 4;

  const size_t base = (size_t)bh * (S_LEN*HDIM);
  const bf16_t* Kg  = Kb   + base + (size_t)(w*16)*HDIM;
  const bf16_t* K2g = K2b  + base + (size_t)(w*16)*HDIM;
  const bf16_t* Vg  = Vblk + base + w*16;

  bf16_t* Kbuf  = smem + w*WBLK;
  bf16_t* K2buf = Kbuf + 2048;
  bf16_t* Vbuf  = K2buf + 2048;             // [64 d][16 j]
  bf16_t* Pbuf  = Vbuf + 1024;              // 2 x [16 i][24] (stride 24 -> 16B-aligned reads)

  // Q fragments (2 q-subtiles x 2 kk) + squared*64 (folds the 1/8 score scale)
  bf16x8_t aq[2][2], aq2[2][2];
#pragma unroll
  for (int qh = 0; qh < 2; ++qh){
    const bf16_t* qrow = Qb + base + (size_t)(qt*32 + qh*16 + qr)*HDIM;
#pragma unroll
    for (int kk = 0; kk < 2; ++kk){
      aq[qh][kk] = *(const bf16x8_t*)(qrow + kk*32 + cg*8);
      bf16x8_t t;
#pragma unroll
      for (int e=0;e<8;e++){ float f = (float)aq[qh][kk][e]; t[e] = (bf16_t)(64.f*f*f); }
      aq2[qh][kk] = t;
    }
  }

  // ---- pass 1: row sums (scores are cosine-bounded: no max tracking) ----
  float lp[2][4] = {{0.f,0.f,0.f,0.f},{0.f,0.f,0.f,0.f}};
  stage_slice16(Kbuf,  Kg,  lane);
  stage_slice16(K2buf, K2g, lane);
  for (int jt = 0; jt < NT; ++jt){
    const int nb = (jt+1) & (NT-1);          // wrap-prefetch keeps vmcnt counts uniform
    __builtin_amdgcn_sched_barrier(0);
    stage_slice16(Kbuf  + ((jt+1)&1)*1024, Kg  + (size_t)nb*64*HDIM, lane);
    stage_slice16(K2buf + ((jt+1)&1)*1024, K2g + (size_t)nb*64*HDIM, lane);
    asm volatile("s_waitcnt vmcnt(4)" ::: "memory");   // current K/K2 landed; prefetch in flight
    __builtin_amdgcn_sched_barrier(0);
    const bf16_t* kb  = Kbuf  + (jt&1)*1024;
    const bf16_t* k2b = K2buf + (jt&1)*1024;
    bf16x8_t kf0  = lds_read8(kb,  qr, cg*8), kf1  = lds_read8(kb,  qr, 32+cg*8);
    bf16x8_t k2f0 = lds_read8(k2b, qr, cg*8), k2f1 = lds_read8(k2b, qr, 32+cg*8);
#pragma unroll
    for (int qh = 0; qh < 2; ++qh){
      f32x4_t nu = {0.f,0.f,0.f,0.f}, nr = {0.f,0.f,0.f,0.f};
      nu = mfma16(aq[qh][0],  kf0,  nu); nu = mfma16(aq[qh][1],  kf1,  nu);
      nr = mfma16(aq2[qh][0], k2f0, nr); nr = mfma16(aq2[qh][1], k2f1, nr);
#pragma unroll
      for (int r=0;r<4;r++){
        const float s = nu[r]*rsqrtf(fmaxf(nr[r], 6.4e-15f));
        lp[qh][r] += __expf(s);
      }
    }
  }

  // cross-lane (16 qr) + cross-wave (4 j-slices) l reduce
#pragma unroll
  for (int qh=0;qh<2;qh++)
#pragma unroll
    for (int r=0;r<4;r++){
      float l = lp[qh][r];
      l += __shfl_xor(l,1); l += __shfl_xor(l,2);
      l += __shfl_xor(l,4); l += __shfl_xor(l,8);
      lred[w][qh][cg*4+r] = l;
    }
  __syncthreads();                          // barrier #1
  float rl[2][4];
#pragma unroll
  for (int qh=0;qh<2;qh++)
#pragma unroll
    for (int r=0;r<4;r++)
      rl[qh][r] = 1.0f/(lred[0][qh][cg*4+r]+lred[1][qh][cg*4+r]
                       +lred[2][qh][cg*4+r]+lred[3][qh][cg*4+r]);

  // ---- pass 2: weights + PV (K/K2 tile 0 in buf0 via pass-1 wrap prefetch) ----
  const f32x4_t zz = {0.f,0.f,0.f,0.f};
  f32x4_t oacc[2][4];
#pragma unroll
  for (int qh=0;qh<2;qh++)
#pragma unroll
    for (int n=0;n<4;n++) oacc[qh][n] = zz;
  const size_t wb = (size_t)bh * S_LEN * S_LEN;
  const bf16x8_t zero8 = {};

  for (int jt = 0; jt < NT; ++jt){
    const int nb = (jt+1) & (NT-1);
    __builtin_amdgcn_sched_barrier(0);
    stage_v(Vbuf, Vg + (size_t)jt*4096, lane);                         // [+2, oldest]
    __builtin_amdgcn_sched_barrier(0);                                 // pin V-first order
    stage_slice16(Kbuf  + ((jt+1)&1)*1024, Kg  + (size_t)nb*64*HDIM, lane);  // [+2]
    stage_slice16(K2buf + ((jt+1)&1)*1024, K2g + (size_t)nb*64*HDIM, lane);  // [+2]
    asm volatile("s_waitcnt vmcnt(6)" ::: "memory");   // K/K2(jt) landed (V+prefetch stay)
    __builtin_amdgcn_sched_barrier(0);
    const bf16_t* kb  = Kbuf  + (jt&1)*1024;
    const bf16_t* k2b = K2buf + (jt&1)*1024;
    bf16x8_t kf0  = lds_read8(kb,  qr, cg*8), kf1  = lds_read8(kb,  qr, 32+cg*8);
    bf16x8_t k2f0 = lds_read8(k2b, qr, cg*8), k2f1 = lds_read8(k2b, qr, 32+cg*8);
#pragma unroll
    for (int qh = 0; qh < 2; ++qh){
      f32x4_t nu = {0.f,0.f,0.f,0.f}, nr = {0.f,0.f,0.f,0.f};
      nu = mfma16(aq[qh][0],  kf0,  nu); nu = mfma16(aq[qh][1],  kf1,  nu);
      nr = mfma16(aq2[qh][0], k2f0, nr); nr = mfma16(aq2[qh][1], k2f1, nr);
#pragma unroll
      for (int r=0;r<4;r++){
        const float s = nu[r]*rsqrtf(fmaxf(nr[r], 6.4e-15f));
        const float wgt = __expf(s) * rl[qh][r];
        const int i = qt*32 + qh*16 + cg*4 + r;
        const int j = jt*64 + w*16 + qr;
        Wout[wb + (size_t)i*S_LEN + j] = wgt;                          // [+8 stores]
        Pbuf[qh*384 + (cg*4+r)*24 + qr] = (bf16_t)wgt;
      }
    }
    asm volatile("s_waitcnt lgkmcnt(0)" ::: "memory");  // P writes visible to own wave
    __builtin_amdgcn_sched_barrier(0);
    asm volatile("s_waitcnt vmcnt(12)" ::: "memory");   // V(jt) landed (prefetch+stores stay)
    __builtin_amdgcn_sched_barrier(0);
    // PV: D[i, d] = sum_j P[i,j] V[j,d]; K=32 MFMA, A zero-padded on cg>=2
    const int k0 = (cg & 1) * 8;
    bf16x8_t pa0 = (cg < 2) ? *(const bf16x8_t*)&Pbuf[      qr*24 + k0] : zero8;
    bf16x8_t pa1 = (cg < 2) ? *(const bf16x8_t*)&Pbuf[384 + qr*24 + k0] : zero8;
#pragma unroll
    for (int n=0;n<4;n++){
      bf16x8_t vb = *(const bf16x8_t*)&Vbuf[(n*16+qr)*16 + k0];
      oacc[0][n] = mfma16(pa0, vb, oacc[0][n]);
      oacc[1][n] = mfma16(pa1, vb, oacc[1][n]);
    }
  }

  // ---- O reduce across the 4 j-slice waves, then epilogue ----
  asm volatile("s_waitcnt vmcnt(0)" ::: "memory");      // drain wrap-stage DMA before reuse
  __builtin_amdgcn_sched_barrier(0);
  float* Ow = (float*)Kbuf;                             // own wave block, stride 68 (pad)
#pragma unroll
  for (int qh=0;qh<2;qh++)
#pragma unroll
    for (int n=0;n<4;n++)
#pragma unroll
      for (int r=0;r<4;r++)
        Ow[(qh*16+cg*4+r)*68 + n*16+qr] = oacc[qh][n][r];
  __syncthreads();                          // barrier #2
  {
    const int row = lane >> 1;              // 0..31
    const int jl  = (lane & 1)*8;
    float v[8];
#pragma unroll
    for (int e=0;e<8;e++) v[e] = 0.f;
#pragma unroll
    for (int ww=0; ww<4; ++ww){
      const float* Os = (const float*)(smem + ww*WBLK);
#pragma unroll
      for (int e=0;e<8;e++) v[e] += Os[row*68 + w*16 + jl + e];
    }
    const int b = bh >> 4, h = bh & 15;
    const int srow = qt*32 + row;
    const size_t o = ((size_t)b*S_LEN + srow)*DMODEL + (size_t)h*HDIM + w*16 + jl;
    bf16x8_t hv, lv;
#pragma unroll
    for (int e=0;e<8;e++){
      bf16_t hb = (bf16_t)v[e]; hv[e] = hb; lv[e] = (bf16_t)(v[e]-(float)hb);
    }
    *(bf16x8_t*)(o1hi + o) = hv;
    *(bf16x8_t*)(o1lo + o) = lv;
  }
}

// ---------------- K3: output projection, split-bf16 GEMM, f32 out ----------------
__global__ __launch_bounds__(256)
void vsa_oproj_kernel(const bf16_t* __restrict__ Ahi_g, const bf16_t* __restrict__ Alo_g,
                      const bf16_t* __restrict__ Bhi_g, const bf16_t* __restrict__ Blo_g,
                      float* __restrict__ out)
{
  __shared__ __align__(16) bf16_t Ah[128][64], Al[128][64], Bh[128][64], Bl[128][64];
  const int m0 = blockIdx.x * 128;
  const int n0 = blockIdx.y * 128;
  const int tid = threadIdx.x, lane = tid & 63, wid = tid >> 6;
  const int wr = (wid >> 1) * 64, wc = (wid & 1) * 64;

  const f32x4_t zz = {0.f,0.f,0.f,0.f};
  f32x4_t acc[4][4];
#pragma unroll
  for (int i=0;i<4;i++)
#pragma unroll
    for (int j=0;j<4;j++) acc[i][j] = zz;

  for (int kt = 0; kt < 16; ++kt){
    const int k0 = kt * 64;
    stage_tile<128>(&Ah[0][0], Ahi_g + (size_t)m0*DMODEL + k0, DMODEL, wid, lane);
    stage_tile<128>(&Al[0][0], Alo_g + (size_t)m0*DMODEL + k0, DMODEL, wid, lane);
    stage_tile<128>(&Bh[0][0], Bhi_g + (size_t)n0*DMODEL + k0, DMODEL, wid, lane);
    stage_tile<128>(&Bl[0][0], Blo_g + (size_t)n0*DMODEL + k0, DMODEL, wid, lane);
    __syncthreads();
#pragma unroll
    for (int kk = 0; kk < 2; ++kk){
      const int ko = kk*32 + (lane>>4)*8;
      bf16x8_t ah[4], al[4], bh4[4], bl4[4];
#pragma unroll
      for (int i=0;i<4;i++){
        const int ar = wr + i*16 + (lane&15);
        const int br = wc + i*16 + (lane&15);
        ah[i]  = lds_read8(&Ah[0][0], ar, ko);
        al[i]  = lds_read8(&Al[0][0], ar, ko);
        bh4[i] = lds_read8(&Bh[0][0], br, ko);
        bl4[i] = lds_read8(&Bl[0][0], br, ko);
      }
#pragma unroll
      for (int i=0;i<4;i++)
#pragma unroll
        for (int j=0;j<4;j++){
          acc[i][j] = mfma16(ah[i], bh4[j], acc[i][j]);
          acc[i][j] = mfma16(ah[i], bl4[j], acc[i][j]);
          acc[i][j] = mfma16(al[i], bh4[j], acc[i][j]);
        }
    }
    __syncthreads();
  }

#pragma unroll
  for (int i=0;i<4;i++)
#pragma unroll
    for (int j=0;j<4;j++)
#pragma unroll
      for (int r=0;r<4;r++){
        const int m = m0 + wr + i*16 + ((lane>>4)<<2) + r;
        const int n = n0 + wc + j*16 + (lane&15);
        out[(size_t)m*DMODEL + n] = acc[i][j][r];
      }
}

extern "C" void kernel_launch(void* const* d_in, const int* in_sizes, int n_in,
                              void* d_out, int out_size, void* d_ws, size_t ws_size,
                              hipStream_t stream)
{
  const float* x  = (const float*)d_in[0];
  const float* Wq = (const float*)d_in[1];
  const float* Wk = (const float*)d_in[2];
  const float* Wv = (const float*)d_in[3];
  const float* Wo = (const float*)d_in[4];
  float* out  = (float*)d_out;
  float* attw = out + (size_t)MTOT*DMODEL;   // tuple output 1: [B,H,S,S]

  // workspace layout (bf16 elements, each slab 4194304 elts = 8 MB)
  bf16_t* ws = (bf16_t*)d_ws;
  const size_t C = 4194304;
  bf16_t* xhi  = ws;
  bf16_t* xlo  = ws + C;
  bf16_t* Whi  = ws + 2*C;   // [4][1024*1024] order q,k,v,o
  bf16_t* Wlo  = ws + 3*C;
  bf16_t* Qb   = ws + 4*C;
  bf16_t* Kb   = ws + 5*C;
  bf16_t* K2b  = ws + 6*C;
  bf16_t* Vblk = ws + 7*C;
  bf16_t* o1hi = ws + 8*C;
  bf16_t* o1lo = ws + 9*C;

  const int W1 = DMODEL*DMODEL; // 1048576
  vsa_split_kernel<<<(int)(C/1024), 256, 0, stream>>>(x,  xhi, xlo, (int)(C/4));
  vsa_split_kernel<<<W1/1024, 256, 0, stream>>>(Wq, Whi + 0*(size_t)W1, Wlo + 0*(size_t)W1, W1/4);
  vsa_split_kernel<<<W1/1024, 256, 0, stream>>>(Wk, Whi + 1*(size_t)W1, Wlo + 1*(size_t)W1, W1/4);
  vsa_split_kernel<<<W1/1024, 256, 0, stream>>>(Wv, Whi + 2*(size_t)W1, Wlo + 2*(size_t)W1, W1/4);
  vsa_split_kernel<<<W1/1024, 256, 0, stream>>>(Wo, Whi + 3*(size_t)W1, Wlo + 3*(size_t)W1, W1/4);

  vsa_qkv_kernel<<<dim3(32, 8, 3), 256, 0, stream>>>(xhi, xlo, Whi, Wlo,
                                                     Qb, Kb, K2b, Vblk);
  vsa_attn_kernel<<<dim3(2048), 256, 0, stream>>>(Qb, Kb, K2b, Vblk,
                                                  attw, o1hi, o1lo);
  vsa_oproj_kernel<<<dim3(32, 8), 256, 0, stream>>>(o1hi, o1lo,
                                                    Whi + 3*(size_t)W1, Wlo + 3*(size_t)W1,
                                                    out);
}

// Round 6
// 356.926 us; speedup vs baseline: 1.5243x; 1.1042x over previous
//
#include <hip/hip_runtime.h>
#include <stdint.h>

typedef __bf16 bf16_t;
typedef __bf16 bf16x4_t __attribute__((ext_vector_type(4)));
typedef __bf16 bf16x8_t __attribute__((ext_vector_type(8)));
typedef float  f32x4_t  __attribute__((ext_vector_type(4)));

#define S_LEN 2048
#define DMODEL 1024
#define NHEAD 16
#define HDIM 64
#define MTOT 4096   // B*S
#define NT 32       // K/V tiles of 64
#define WBLK 4864   // per-wave LDS elems: K[2] 2048 | V[2] 2048 | P 768

__device__ __forceinline__ f32x4_t mfma16(bf16x8_t a, bf16x8_t b, f32x4_t c){
  return __builtin_amdgcn_mfma_f32_16x16x32_bf16(a, b, c, 0, 0, 0);
}

__device__ __forceinline__ void gload_lds16(const bf16_t* g, bf16_t* l){
  __builtin_amdgcn_global_load_lds(
      (const __attribute__((address_space(1))) void*)(uintptr_t)g,
      (__attribute__((address_space(3))) void*)(uintptr_t)l,
      16, 0, 0);
}

// ---- XOR-swizzled [ROWS][64] staging (linear LDS dest, pre-swizzled source) ----
template<int ROWS>
__device__ __forceinline__ void stage_tile(bf16_t* lds, const bf16_t* __restrict__ g,
                                           int ldg, int wid, int lane){
  const int rl = lane >> 3;
  const int cs = ((lane & 7) ^ rl) << 3;
#pragma unroll
  for (int it = 0; it < ROWS/32; ++it){
    const int chunk = it*4 + wid;
    gload_lds16(g + (size_t)(chunk*8 + rl)*ldg + cs, lds + chunk*512);
  }
}

// wave-level [16][64] slice (2 gload_lds), same swizzle
__device__ __forceinline__ void stage_slice16(bf16_t* lds, const bf16_t* __restrict__ g,
                                              int lane){
  const int rl = lane >> 3;
  const int cs = ((lane & 7) ^ rl) << 3;
#pragma unroll
  for (int c = 0; c < 2; ++c)
    gload_lds16(g + (size_t)(c*8 + rl)*HDIM + cs, lds + c*512);
}

// wave-level V slice [64 d][16 j] from Vblk tile [64 d][64 j] (linear, no swizzle)
__device__ __forceinline__ void stage_v(bf16_t* lds, const bf16_t* __restrict__ g,
                                        int lane){
#pragma unroll
  for (int c = 0; c < 2; ++c)
    gload_lds16(g + (size_t)(c*32 + (lane>>1))*64 + (lane&1)*8, lds + c*512);
}

__device__ __forceinline__ bf16x8_t lds_read8(const bf16_t* t, int row, int ko){
  return *(const bf16x8_t*)&t[row*64 + (ko ^ ((row & 7) << 3))];
}

__device__ __forceinline__ bf16x8_t sq8(bf16x8_t v){
  bf16x8_t r;
#pragma unroll
  for (int i=0;i<8;i++){ float f = (float)v[i]; r[i] = (bf16_t)(f*f); }
  return r;
}

// ---------------- K0: f32 -> bf16 hi/lo split ----------------
__global__ __launch_bounds__(256)
void vsa_split_kernel(const float* __restrict__ src, bf16_t* __restrict__ hi,
                      bf16_t* __restrict__ lo, int n4){
  int i = blockIdx.x*256 + threadIdx.x;
  if (i >= n4) return;
  float4 v = ((const float4*)src)[i];
  bf16_t h0=(bf16_t)v.x, h1=(bf16_t)v.y, h2=(bf16_t)v.z, h3=(bf16_t)v.w;
  bf16x4_t hv = {h0,h1,h2,h3};
  bf16x4_t lv = {(bf16_t)(v.x-(float)h0),(bf16_t)(v.y-(float)h1),
                 (bf16_t)(v.z-(float)h2),(bf16_t)(v.w-(float)h3)};
  ((bf16x4_t*)hi)[i] = hv;
  ((bf16x4_t*)lo)[i] = lv;
}

// ---------------- K1: QKV projection, split-bf16 (3-MFMA) GEMM ----------------
__global__ __launch_bounds__(256)
void vsa_qkv_kernel(const bf16_t* __restrict__ xhi, const bf16_t* __restrict__ xlo,
                    const bf16_t* __restrict__ Whi, const bf16_t* __restrict__ Wlo,
                    bf16_t* __restrict__ Qb, bf16_t* __restrict__ Kb,
                    bf16_t* __restrict__ Vblk)
{
  __shared__ __align__(16) bf16_t Ah[128][64], Al[128][64], Bh[128][64], Bl[128][64];
  const int z  = blockIdx.z;                 // 0=Q,1=K,2=V
  const int m0 = blockIdx.x * 128;
  const int n0 = blockIdx.y * 128;
  const int tid = threadIdx.x, lane = tid & 63, wid = tid >> 6;
  const int wr = (wid >> 1) * 64, wc = (wid & 1) * 64;
  const bf16_t* Wh = Whi + (size_t)z * (DMODEL*DMODEL);
  const bf16_t* Wl = Wlo + (size_t)z * (DMODEL*DMODEL);

  const f32x4_t zz = {0.f,0.f,0.f,0.f};
  f32x4_t acc[4][4];
#pragma unroll
  for (int i=0;i<4;i++)
#pragma unroll
    for (int j=0;j<4;j++) acc[i][j] = zz;

  for (int kt = 0; kt < 16; ++kt){
    const int k0 = kt * 64;
    stage_tile<128>(&Ah[0][0], xhi + (size_t)m0*DMODEL + k0, DMODEL, wid, lane);
    stage_tile<128>(&Al[0][0], xlo + (size_t)m0*DMODEL + k0, DMODEL, wid, lane);
    stage_tile<128>(&Bh[0][0], Wh  + (size_t)n0*DMODEL + k0, DMODEL, wid, lane);
    stage_tile<128>(&Bl[0][0], Wl  + (size_t)n0*DMODEL + k0, DMODEL, wid, lane);
    __syncthreads();
#pragma unroll
    for (int kk = 0; kk < 2; ++kk){
      const int ko = kk*32 + (lane>>4)*8;
      bf16x8_t ah[4], al[4], bh4[4], bl4[4];
#pragma unroll
      for (int i=0;i<4;i++){
        const int ar = wr + i*16 + (lane&15);
        const int br = wc + i*16 + (lane&15);
        ah[i]  = lds_read8(&Ah[0][0], ar, ko);
        al[i]  = lds_read8(&Al[0][0], ar, ko);
        bh4[i] = lds_read8(&Bh[0][0], br, ko);
        bl4[i] = lds_read8(&Bl[0][0], br, ko);
      }
#pragma unroll
      for (int i=0;i<4;i++)
#pragma unroll
        for (int j=0;j<4;j++){
          acc[i][j] = mfma16(ah[i], bh4[j], acc[i][j]);
          acc[i][j] = mfma16(ah[i], bl4[j], acc[i][j]);
          acc[i][j] = mfma16(al[i], bh4[j], acc[i][j]);
        }
    }
    __syncthreads();
  }

#pragma unroll
  for (int i=0;i<4;i++)
#pragma unroll
    for (int j=0;j<4;j++)
#pragma unroll
      for (int r=0;r<4;r++){
        const int m = m0 + wr + i*16 + ((lane>>4)<<2) + r;
        const int n = n0 + wc + j*16 + (lane&15);
        const float q = acc[i][j][r];
        const int b = m >> 11, s = m & 2047, h = n >> 6, d = n & 63;
        const size_t bh_ = (size_t)b*NHEAD + h;
        if (z == 0){
          Qb[(bh_*S_LEN + s)*HDIM + d] = (bf16_t)q;
        } else if (z == 1){
          Kb[(bh_*S_LEN + s)*HDIM + d] = (bf16_t)q;
        } else {
          // V block-transposed: [bh][s/64][64 d][64 j]
          Vblk[bh_*(size_t)(S_LEN*HDIM) + (size_t)(s>>6)*4096 + d*64 + (s&63)] = (bf16_t)q;
        }
      }
}

// ---------------- K2: attention, barrier-free wave-owned j-slices ----------
// Grid 2048 = (qt 0..63) x (bh 0..31), bh-major XCD swizzle.
// WG = 32 q-rows, 4 waves; wave w owns j-slice [jt*64 + w*16, +16).
// K^2 computed IN-REGISTER from K fragments (no K2 stream at all).
// Store-aware counted vmcnt: loads(j) < stores(j-1)[8] < loads(j+1)[4]
//   -> vmcnt(12) drains exactly loads(j).
__global__ __launch_bounds__(256, 4)
void vsa_attn_kernel(const bf16_t* __restrict__ Qb,
                     const bf16_t* __restrict__ Kb,
                     const bf16_t* __restrict__ Vblk,
                     float* __restrict__ Wout,
                     bf16_t* __restrict__ o1hi, bf16_t* __restrict__ o1lo)
{
  __shared__ __align__(16) bf16_t smem[4*WBLK];
  __shared__ float lred[4][2][16];

  const int lin = blockIdx.x;               // 0..2047
  const int xcd = lin & 7;
  const int idx = lin >> 3;                 // 0..255
  const int qt  = idx & 63;                 // 64 q-tiles of 32 rows
  const int bh  = xcd + 8*(idx >> 6);       // 4 heads per XCD -> K/V L2-resident
  const int lane = threadIdx.x & 63, w = (int)(threadIdx.x >> 6);
  const int qr = lane & 15, cg = lane >> 4;

  const size_t base = (size_t)bh * (S_LEN*HDIM);
  const bf16_t* Kg = Kb   + base + (size_t)(w*16)*HDIM;
  const bf16_t* Vg = Vblk + base + w*16;

  bf16_t* Kbuf = smem + w*WBLK;             // [2][16][64] swizzled
  bf16_t* Vbuf = Kbuf + 2048;               // [2][64 d][16 j]
  bf16_t* Pbuf = Vbuf + 2048;               // 2 x [16 i][24]

  // Q fragments (2 q-subtiles x 2 kk) + squared*64 (folds the 1/8 score scale)
  bf16x8_t aq[2][2], aq2[2][2];
#pragma unroll
  for (int qh = 0; qh < 2; ++qh){
    const bf16_t* qrow = Qb + base + (size_t)(qt*32 + qh*16 + qr)*HDIM;
#pragma unroll
    for (int kk = 0; kk < 2; ++kk){
      aq[qh][kk] = *(const bf16x8_t*)(qrow + kk*32 + cg*8);
      bf16x8_t t;
#pragma unroll
      for (int e=0;e<8;e++){ float f = (float)aq[qh][kk][e]; t[e] = (bf16_t)(64.f*f*f); }
      aq2[qh][kk] = t;
    }
  }

  // ---- pass 1: row sums (scores are cosine-bounded: no max tracking) ----
  float lp[2][4] = {{0.f,0.f,0.f,0.f},{0.f,0.f,0.f,0.f}};
  stage_slice16(Kbuf, Kg, lane);
  for (int jt = 0; jt < NT; ++jt){
    const int nb = (jt+1) & (NT-1);          // wrap-prefetch keeps counts uniform
    __builtin_amdgcn_sched_barrier(0);
    stage_slice16(Kbuf + ((jt+1)&1)*1024, Kg + (size_t)nb*64*HDIM, lane);  // [+2]
    asm volatile("s_waitcnt vmcnt(2)" ::: "memory");   // K(jt) landed; prefetch in flight
    __builtin_amdgcn_sched_barrier(0);
    const bf16_t* kb = Kbuf + (jt&1)*1024;
    bf16x8_t kf0  = lds_read8(kb, qr, cg*8), kf1 = lds_read8(kb, qr, 32+cg*8);
    bf16x8_t k2f0 = sq8(kf0),                k2f1 = sq8(kf1);
#pragma unroll
    for (int qh = 0; qh < 2; ++qh){
      f32x4_t nu = {0.f,0.f,0.f,0.f}, nr = {0.f,0.f,0.f,0.f};
      nu = mfma16(aq[qh][0],  kf0,  nu); nu = mfma16(aq[qh][1],  kf1,  nu);
      nr = mfma16(aq2[qh][0], k2f0, nr); nr = mfma16(aq2[qh][1], k2f1, nr);
#pragma unroll
      for (int r=0;r<4;r++){
        const float s = nu[r]*rsqrtf(fmaxf(nr[r], 6.4e-15f));
        lp[qh][r] += __expf(s);
      }
    }
  }

  // cross-lane (16 qr) + cross-wave (4 j-slices) l reduce
#pragma unroll
  for (int qh=0;qh<2;qh++)
#pragma unroll
    for (int r=0;r<4;r++){
      float l = lp[qh][r];
      l += __shfl_xor(l,1); l += __shfl_xor(l,2);
      l += __shfl_xor(l,4); l += __shfl_xor(l,8);
      lred[w][qh][cg*4+r] = l;
    }
  __syncthreads();                          // barrier #1 (drains all DMA; K tile0 in buf0)
  float rl[2][4];
#pragma unroll
  for (int qh=0;qh<2;qh++)
#pragma unroll
    for (int r=0;r<4;r++)
      rl[qh][r] = 1.0f/(lred[0][qh][cg*4+r]+lred[1][qh][cg*4+r]
                       +lred[2][qh][cg*4+r]+lred[3][qh][cg*4+r]);

  // ---- pass 2: weights + PV ----
  const f32x4_t zz = {0.f,0.f,0.f,0.f};
  f32x4_t oacc[2][4];
#pragma unroll
  for (int qh=0;qh<2;qh++)
#pragma unroll
    for (int n=0;n<4;n++) oacc[qh][n] = zz;
  const size_t wb = (size_t)bh * S_LEN * S_LEN;
  const bf16x8_t zero8 = {};

  // prologue: V(0) (K(0) already in Kbuf[0] via pass-1 wrap prefetch)
  stage_v(Vbuf, Vg, lane);
  asm volatile("s_waitcnt vmcnt(0)" ::: "memory");
  __builtin_amdgcn_sched_barrier(0);

  for (int jt = 0; jt < NT; ++jt){
    const int nb = (jt+1) & (NT-1);
    __builtin_amdgcn_sched_barrier(0);
    stage_slice16(Kbuf + ((jt+1)&1)*1024, Kg + (size_t)nb*64*HDIM, lane);  // [+2]
    stage_v(Vbuf + ((jt+1)&1)*1024, Vg + (size_t)nb*4096, lane);           // [+2]
    // steady state: loads(jt)[4, oldest] < stores(jt-1)[8] < loads(jt+1)[4]
    asm volatile("s_waitcnt vmcnt(12)" ::: "memory");  // K/V(jt) landed
    __builtin_amdgcn_sched_barrier(0);
    const bf16_t* kb = Kbuf + (jt&1)*1024;
    bf16x8_t kf0  = lds_read8(kb, qr, cg*8), kf1 = lds_read8(kb, qr, 32+cg*8);
    bf16x8_t k2f0 = sq8(kf0),                k2f1 = sq8(kf1);
#pragma unroll
    for (int qh = 0; qh < 2; ++qh){
      f32x4_t nu = {0.f,0.f,0.f,0.f}, nr = {0.f,0.f,0.f,0.f};
      nu = mfma16(aq[qh][0],  kf0,  nu); nu = mfma16(aq[qh][1],  kf1,  nu);
      nr = mfma16(aq2[qh][0], k2f0, nr); nr = mfma16(aq2[qh][1], k2f1, nr);
#pragma unroll
      for (int r=0;r<4;r++){
        const float s = nu[r]*rsqrtf(fmaxf(nr[r], 6.4e-15f));
        const float wgt = __expf(s) * rl[qh][r];
        const int i = qt*32 + qh*16 + cg*4 + r;
        const int j = jt*64 + w*16 + qr;
        Wout[wb + (size_t)i*S_LEN + j] = wgt;                          // [8 stores]
        Pbuf[qh*384 + (cg*4+r)*24 + qr] = (bf16_t)wgt;
      }
    }
    asm volatile("s_waitcnt lgkmcnt(0)" ::: "memory");  // P writes visible to own wave
    __builtin_amdgcn_sched_barrier(0);
    // PV: D[i,d] = sum_j P[i,j] V[j,d]; K=32 MFMA, A zero-padded on cg>=2
    const int k0 = (cg & 1) * 8;
    bf16x8_t pa0 = (cg < 2) ? *(const bf16x8_t*)&Pbuf[      qr*24 + k0] : zero8;
    bf16x8_t pa1 = (cg < 2) ? *(const bf16x8_t*)&Pbuf[384 + qr*24 + k0] : zero8;
    const bf16_t* vbase = Vbuf + (jt&1)*1024;
#pragma unroll
    for (int n=0;n<4;n++){
      bf16x8_t vb = *(const bf16x8_t*)&vbase[(n*16+qr)*16 + k0];
      oacc[0][n] = mfma16(pa0, vb, oacc[0][n]);
      oacc[1][n] = mfma16(pa1, vb, oacc[1][n]);
    }
  }

  // ---- O reduce across the 4 j-slice waves, then epilogue ----
  asm volatile("s_waitcnt vmcnt(0)" ::: "memory");      // drain wrap-stage DMA before reuse
  __builtin_amdgcn_sched_barrier(0);
  float* Ow = (float*)Kbuf;                             // own wave block, stride 68 (pad)
#pragma unroll
  for (int qh=0;qh<2;qh++)
#pragma unroll
    for (int n=0;n<4;n++)
#pragma unroll
      for (int r=0;r<4;r++)
        Ow[(qh*16+cg*4+r)*68 + n*16+qr] = oacc[qh][n][r];
  __syncthreads();                          // barrier #2
  {
    const int row = lane >> 1;              // 0..31
    const int jl  = (lane & 1)*8;
    float v[8];
#pragma unroll
    for (int e=0;e<8;e++) v[e] = 0.f;
#pragma unroll
    for (int ww=0; ww<4; ++ww){
      const float* Os = (const float*)(smem + ww*WBLK);
#pragma unroll
      for (int e=0;e<8;e++) v[e] += Os[row*68 + w*16 + jl + e];
    }
    const int b = bh >> 4, h = bh & 15;
    const int srow = qt*32 + row;
    const size_t o = ((size_t)b*S_LEN + srow)*DMODEL + (size_t)h*HDIM + w*16 + jl;
    bf16x8_t hv, lv;
#pragma unroll
    for (int e=0;e<8;e++){
      bf16_t hb = (bf16_t)v[e]; hv[e] = hb; lv[e] = (bf16_t)(v[e]-(float)hb);
    }
    *(bf16x8_t*)(o1hi + o) = hv;
    *(bf16x8_t*)(o1lo + o) = lv;
  }
}

// ---------------- K3: output projection, split-bf16 GEMM, f32 out ----------------
__global__ __launch_bounds__(256)
void vsa_oproj_kernel(const bf16_t* __restrict__ Ahi_g, const bf16_t* __restrict__ Alo_g,
                      const bf16_t* __restrict__ Bhi_g, const bf16_t* __restrict__ Blo_g,
                      float* __restrict__ out)
{
  __shared__ __align__(16) bf16_t Ah[128][64], Al[128][64], Bh[128][64], Bl[128][64];
  const int m0 = blockIdx.x * 128;
  const int n0 = blockIdx.y * 128;
  const int tid = threadIdx.x, lane = tid & 63, wid = tid >> 6;
  const int wr = (wid >> 1) * 64, wc = (wid & 1) * 64;

  const f32x4_t zz = {0.f,0.f,0.f,0.f};
  f32x4_t acc[4][4];
#pragma unroll
  for (int i=0;i<4;i++)
#pragma unroll
    for (int j=0;j<4;j++) acc[i][j] = zz;

  for (int kt = 0; kt < 16; ++kt){
    const int k0 = kt * 64;
    stage_tile<128>(&Ah[0][0], Ahi_g + (size_t)m0*DMODEL + k0, DMODEL, wid, lane);
    stage_tile<128>(&Al[0][0], Alo_g + (size_t)m0*DMODEL + k0, DMODEL, wid, lane);
    stage_tile<128>(&Bh[0][0], Bhi_g + (size_t)n0*DMODEL + k0, DMODEL, wid, lane);
    stage_tile<128>(&Bl[0][0], Blo_g + (size_t)n0*DMODEL + k0, DMODEL, wid, lane);
    __syncthreads();
#pragma unroll
    for (int kk = 0; kk < 2; ++kk){
      const int ko = kk*32 + (lane>>4)*8;
      bf16x8_t ah[4], al[4], bh4[4], bl4[4];
#pragma unroll
      for (int i=0;i<4;i++){
        const int ar = wr + i*16 + (lane&15);
        const int br = wc + i*16 + (lane&15);
        ah[i]  = lds_read8(&Ah[0][0], ar, ko);
        al[i]  = lds_read8(&Al[0][0], ar, ko);
        bh4[i] = lds_read8(&Bh[0][0], br, ko);
        bl4[i] = lds_read8(&Bl[0][0], br, ko);
      }
#pragma unroll
      for (int i=0;i<4;i++)
#pragma unroll
        for (int j=0;j<4;j++){
          acc[i][j] = mfma16(ah[i], bh4[j], acc[i][j]);
          acc[i][j] = mfma16(ah[i], bl4[j], acc[i][j]);
          acc[i][j] = mfma16(al[i], bh4[j], acc[i][j]);
        }
    }
    __syncthreads();
  }

#pragma unroll
  for (int i=0;i<4;i++)
#pragma unroll
    for (int j=0;j<4;j++)
#pragma unroll
      for (int r=0;r<4;r++){
        const int m = m0 + wr + i*16 + ((lane>>4)<<2) + r;
        const int n = n0 + wc + j*16 + (lane&15);
        out[(size_t)m*DMODEL + n] = acc[i][j][r];
      }
}

extern "C" void kernel_launch(void* const* d_in, const int* in_sizes, int n_in,
                              void* d_out, int out_size, void* d_ws, size_t ws_size,
                              hipStream_t stream)
{
  const float* x  = (const float*)d_in[0];
  const float* Wq = (const float*)d_in[1];
  const float* Wk = (const float*)d_in[2];
  const float* Wv = (const float*)d_in[3];
  const float* Wo = (const float*)d_in[4];
  float* out  = (float*)d_out;
  float* attw = out + (size_t)MTOT*DMODEL;   // tuple output 1: [B,H,S,S]

  // workspace layout (bf16 elements, each slab 4194304 elts = 8 MB)
  bf16_t* ws = (bf16_t*)d_ws;
  const size_t C = 4194304;
  bf16_t* xhi  = ws;
  bf16_t* xlo  = ws + C;
  bf16_t* Whi  = ws + 2*C;   // [4][1024*1024] order q,k,v,o
  bf16_t* Wlo  = ws + 3*C;
  bf16_t* Qb   = ws + 4*C;
  bf16_t* Kb   = ws + 5*C;
  bf16_t* Vblk = ws + 6*C;
  bf16_t* o1hi = ws + 7*C;
  bf16_t* o1lo = ws + 8*C;

  const int W1 = DMODEL*DMODEL; // 1048576
  vsa_split_kernel<<<(int)(C/1024), 256, 0, stream>>>(x,  xhi, xlo, (int)(C/4));
  vsa_split_kernel<<<W1/1024, 256, 0, stream>>>(Wq, Whi + 0*(size_t)W1, Wlo + 0*(size_t)W1, W1/4);
  vsa_split_kernel<<<W1/1024, 256, 0, stream>>>(Wk, Whi + 1*(size_t)W1, Wlo + 1*(size_t)W1, W1/4);
  vsa_split_kernel<<<W1/1024, 256, 0, stream>>>(Wv, Whi + 2*(size_t)W1, Wlo + 2*(size_t)W1, W1/4);
  vsa_split_kernel<<<W1/1024, 256, 0, stream>>>(Wo, Whi + 3*(size_t)W1, Wlo + 3*(size_t)W1, W1/4);

  vsa_qkv_kernel<<<dim3(32, 8, 3), 256, 0, stream>>>(xhi, xlo, Whi, Wlo,
                                                     Qb, Kb, Vblk);
  vsa_attn_kernel<<<dim3(2048), 256, 0, stream>>>(Qb, Kb, Vblk,
                                                  attw, o1hi, o1lo);
  vsa_oproj_kernel<<<dim3(32, 8), 256, 0, stream>>>(o1hi, o1lo,
                                                    Whi + 3*(size_t)W1, Wlo + 3*(size_t)W1,
                                                    out);
}

// Round 7
// 306.743 us; speedup vs baseline: 1.7737x; 1.1636x over previous
//
#include <hip/hip_runtime.h>
#include <stdint.h>

typedef __bf16 bf16_t;
typedef __bf16 bf16x4_t __attribute__((ext_vector_type(4)));
typedef __bf16 bf16x8_t __attribute__((ext_vector_type(8)));
typedef float  f32x4_t  __attribute__((ext_vector_type(4)));

#define S_LEN 2048
#define DMODEL 1024
#define NHEAD 16
#define HDIM 64
#define MTOT 4096   // B*S
#define NT 32       // K/V tiles of 64
#define WBLK 4864   // per-wave LDS elems: K[2] 2048 | V[2] 2048 | P 768

__device__ __forceinline__ f32x4_t mfma16(bf16x8_t a, bf16x8_t b, f32x4_t c){
  return __builtin_amdgcn_mfma_f32_16x16x32_bf16(a, b, c, 0, 0, 0);
}

__device__ __forceinline__ void gload_lds16(const bf16_t* g, bf16_t* l){
  __builtin_amdgcn_global_load_lds(
      (const __attribute__((address_space(1))) void*)(uintptr_t)g,
      (__attribute__((address_space(3))) void*)(uintptr_t)l,
      16, 0, 0);
}

// ---- XOR-swizzled [ROWS][64] staging (linear LDS dest, pre-swizzled source) ----
template<int ROWS>
__device__ __forceinline__ void stage_tile(bf16_t* lds, const bf16_t* __restrict__ g,
                                           int ldg, int wid, int lane){
  const int rl = lane >> 3;
  const int cs = ((lane & 7) ^ rl) << 3;
#pragma unroll
  for (int it = 0; it < ROWS/32; ++it){
    const int chunk = it*4 + wid;
    gload_lds16(g + (size_t)(chunk*8 + rl)*ldg + cs, lds + chunk*512);
  }
}

// wave-level [16][64] slice (2 gload_lds), same swizzle
__device__ __forceinline__ void stage_slice16(bf16_t* lds, const bf16_t* __restrict__ g,
                                              int lane){
  const int rl = lane >> 3;
  const int cs = ((lane & 7) ^ rl) << 3;
#pragma unroll
  for (int c = 0; c < 2; ++c)
    gload_lds16(g + (size_t)(c*8 + rl)*HDIM + cs, lds + c*512);
}

// wave-level V slice, LDS layout [2 jh][64 d][8 j] (16B rows -> no bank clash).
// DMA is linear: issue c covers jh=c; lane l covers d=l, j = c*8..c*8+7.
__device__ __forceinline__ void stage_v(bf16_t* lds, const bf16_t* __restrict__ g,
                                        int lane){
#pragma unroll
  for (int c = 0; c < 2; ++c)
    gload_lds16(g + (size_t)lane*64 + c*8, lds + c*512);
}

__device__ __forceinline__ bf16x8_t lds_read8(const bf16_t* t, int row, int ko){
  return *(const bf16x8_t*)&t[row*64 + (ko ^ ((row & 7) << 3))];
}

__device__ __forceinline__ bf16x8_t sq8(bf16x8_t v){
  bf16x8_t r;
#pragma unroll
  for (int i=0;i<8;i++){ float f = (float)v[i]; r[i] = (bf16_t)(f*f); }
  return r;
}

// ---------------- K0: f32 -> bf16 cast ----------------
__global__ __launch_bounds__(256)
void vsa_cast_kernel(const float* __restrict__ src, bf16_t* __restrict__ dst, int n4){
  int i = blockIdx.x*256 + threadIdx.x;
  if (i >= n4) return;
  float4 v = ((const float4*)src)[i];
  bf16x4_t o = {(bf16_t)v.x,(bf16_t)v.y,(bf16_t)v.z,(bf16_t)v.w};
  ((bf16x4_t*)dst)[i] = o;
}

// ---------------- K1: QKV projection, plain bf16 GEMM ----------------
// 128x128 tile, BK=64, 4 waves, LDS 32 KB -> 3 WG/CU co-resident (grid 768).
__global__ __launch_bounds__(256)
void vsa_qkv_kernel(const bf16_t* __restrict__ xb, const bf16_t* __restrict__ Wb,
                    bf16_t* __restrict__ Qb, bf16_t* __restrict__ Kb,
                    bf16_t* __restrict__ Vblk)
{
  __shared__ __align__(16) bf16_t Ah[128][64], Bh[128][64];
  const int z  = blockIdx.z;                 // 0=Q,1=K,2=V
  const int m0 = blockIdx.x * 128;
  const int n0 = blockIdx.y * 128;
  const int tid = threadIdx.x, lane = tid & 63, wid = tid >> 6;
  const int wr = (wid >> 1) * 64, wc = (wid & 1) * 64;
  const bf16_t* Wz = Wb + (size_t)z * (DMODEL*DMODEL);

  const f32x4_t zz = {0.f,0.f,0.f,0.f};
  f32x4_t acc[4][4];
#pragma unroll
  for (int i=0;i<4;i++)
#pragma unroll
    for (int j=0;j<4;j++) acc[i][j] = zz;

  for (int kt = 0; kt < 16; ++kt){
    const int k0 = kt * 64;
    stage_tile<128>(&Ah[0][0], xb + (size_t)m0*DMODEL + k0, DMODEL, wid, lane);
    stage_tile<128>(&Bh[0][0], Wz + (size_t)n0*DMODEL + k0, DMODEL, wid, lane);
    __syncthreads();
#pragma unroll
    for (int kk = 0; kk < 2; ++kk){
      const int ko = kk*32 + (lane>>4)*8;
      bf16x8_t ah[4], bh4[4];
#pragma unroll
      for (int i=0;i<4;i++){
        ah[i]  = lds_read8(&Ah[0][0], wr + i*16 + (lane&15), ko);
        bh4[i] = lds_read8(&Bh[0][0], wc + i*16 + (lane&15), ko);
      }
#pragma unroll
      for (int i=0;i<4;i++)
#pragma unroll
        for (int j=0;j<4;j++)
          acc[i][j] = mfma16(ah[i], bh4[j], acc[i][j]);
    }
    __syncthreads();
  }

#pragma unroll
  for (int i=0;i<4;i++)
#pragma unroll
    for (int j=0;j<4;j++)
#pragma unroll
      for (int r=0;r<4;r++){
        const int m = m0 + wr + i*16 + ((lane>>4)<<2) + r;
        const int n = n0 + wc + j*16 + (lane&15);
        const float q = acc[i][j][r];
        const int b = m >> 11, s = m & 2047, h = n >> 6, d = n & 63;
        const size_t bh_ = (size_t)b*NHEAD + h;
        if (z == 0){
          Qb[(bh_*S_LEN + s)*HDIM + d] = (bf16_t)q;
        } else if (z == 1){
          Kb[(bh_*S_LEN + s)*HDIM + d] = (bf16_t)q;
        } else {
          // V block-transposed: [bh][s/64][64 d][64 j]
          Vblk[bh_*(size_t)(S_LEN*HDIM) + (size_t)(s>>6)*4096 + d*64 + (s&63)] = (bf16_t)q;
        }
      }
}

// ---------------- K2: attention, barrier-free wave-owned j-slices ----------
// Grid 2048 = (qt 0..63) x (bh 0..31), bh-major XCD swizzle.
// WG = 32 q-rows, 4 waves; wave w owns j-slice [jt*64 + w*16, +16).
// K^2 in-register; store-aware counted vmcnt (loads(j) < stores(j-1)[8] <
// loads(j+1)[4] -> vmcnt(12) drains exactly loads(j)).
__global__ __launch_bounds__(256, 4)
void vsa_attn_kernel(const bf16_t* __restrict__ Qb,
                     const bf16_t* __restrict__ Kb,
                     const bf16_t* __restrict__ Vblk,
                     float* __restrict__ Wout,
                     bf16_t* __restrict__ o1)
{
  __shared__ __align__(16) bf16_t smem[4*WBLK];
  __shared__ float lred[4][2][16];

  const int lin = blockIdx.x;               // 0..2047
  const int xcd = lin & 7;
  const int idx = lin >> 3;                 // 0..255
  const int qt  = idx & 63;                 // 64 q-tiles of 32 rows
  const int bh  = xcd + 8*(idx >> 6);       // 4 heads per XCD -> K/V L2-resident
  const int lane = threadIdx.x & 63, w = (int)(threadIdx.x >> 6);
  const int qr = lane & 15, cg = lane >> 4;

  const size_t base = (size_t)bh * (S_LEN*HDIM);
  const bf16_t* Kg = Kb   + base + (size_t)(w*16)*HDIM;
  const bf16_t* Vg = Vblk + base + w*16;    // wave's 16-j column window

  bf16_t* Kbuf = smem + w*WBLK;             // [2][16][64] swizzled
  bf16_t* Vbuf = Kbuf + 2048;               // [2][2 jh][64 d][8 j]
  bf16_t* Pbuf = Vbuf + 2048;               // 2 x [16 i][24]

  // Q fragments (2 q-subtiles x 2 kk) + squared*64 (folds the 1/8 score scale)
  bf16x8_t aq[2][2], aq2[2][2];
#pragma unroll
  for (int qh = 0; qh < 2; ++qh){
    const bf16_t* qrow = Qb + base + (size_t)(qt*32 + qh*16 + qr)*HDIM;
#pragma unroll
    for (int kk = 0; kk < 2; ++kk){
      aq[qh][kk] = *(const bf16x8_t*)(qrow + kk*32 + cg*8);
      bf16x8_t t;
#pragma unroll
      for (int e=0;e<8;e++){ float f = (float)aq[qh][kk][e]; t[e] = (bf16_t)(64.f*f*f); }
      aq2[qh][kk] = t;
    }
  }

  // ---- pass 1: row sums (scores are cosine-bounded: no max tracking) ----
  float lp[2][4] = {{0.f,0.f,0.f,0.f},{0.f,0.f,0.f,0.f}};
  stage_slice16(Kbuf, Kg, lane);
  for (int jt = 0; jt < NT; ++jt){
    const int nb = (jt+1) & (NT-1);          // wrap-prefetch keeps counts uniform
    __builtin_amdgcn_sched_barrier(0);
    stage_slice16(Kbuf + ((jt+1)&1)*1024, Kg + (size_t)nb*64*HDIM, lane);  // [+2]
    asm volatile("s_waitcnt vmcnt(2)" ::: "memory");   // K(jt) landed; prefetch in flight
    __builtin_amdgcn_sched_barrier(0);
    const bf16_t* kb = Kbuf + (jt&1)*1024;
    bf16x8_t kf0  = lds_read8(kb, qr, cg*8), kf1 = lds_read8(kb, qr, 32+cg*8);
    bf16x8_t k2f0 = sq8(kf0),                k2f1 = sq8(kf1);
    f32x4_t nu[2], nr[2];
    __builtin_amdgcn_s_setprio(1);
#pragma unroll
    for (int qh = 0; qh < 2; ++qh){
      f32x4_t a = {0.f,0.f,0.f,0.f}, b = {0.f,0.f,0.f,0.f};
      a = mfma16(aq[qh][0],  kf0,  a); a = mfma16(aq[qh][1],  kf1,  a);
      b = mfma16(aq2[qh][0], k2f0, b); b = mfma16(aq2[qh][1], k2f1, b);
      nu[qh] = a; nr[qh] = b;
    }
    __builtin_amdgcn_s_setprio(0);
#pragma unroll
    for (int qh = 0; qh < 2; ++qh)
#pragma unroll
      for (int r=0;r<4;r++){
        const float s = nu[qh][r]*rsqrtf(fmaxf(nr[qh][r], 6.4e-15f));
        lp[qh][r] += __expf(s);
      }
  }

  // cross-lane (16 qr) + cross-wave (4 j-slices) l reduce
#pragma unroll
  for (int qh=0;qh<2;qh++)
#pragma unroll
    for (int r=0;r<4;r++){
      float l = lp[qh][r];
      l += __shfl_xor(l,1); l += __shfl_xor(l,2);
      l += __shfl_xor(l,4); l += __shfl_xor(l,8);
      lred[w][qh][cg*4+r] = l;
    }
  __syncthreads();                          // barrier #1 (drains all DMA; K tile0 in buf0)
  float rl[2][4];
#pragma unroll
  for (int qh=0;qh<2;qh++)
#pragma unroll
    for (int r=0;r<4;r++)
      rl[qh][r] = 1.0f/(lred[0][qh][cg*4+r]+lred[1][qh][cg*4+r]
                       +lred[2][qh][cg*4+r]+lred[3][qh][cg*4+r]);

  // ---- pass 2: weights + PV ----
  const f32x4_t zz = {0.f,0.f,0.f,0.f};
  f32x4_t oacc[2][4];
#pragma unroll
  for (int qh=0;qh<2;qh++)
#pragma unroll
    for (int n=0;n<4;n++) oacc[qh][n] = zz;
  const size_t wb = (size_t)bh * S_LEN * S_LEN;
  const bf16x8_t zero8 = {};

  // prologue: V(0) (K(0) already in Kbuf[0] via pass-1 wrap prefetch)
  stage_v(Vbuf, Vg, lane);
  asm volatile("s_waitcnt vmcnt(0)" ::: "memory");
  __builtin_amdgcn_sched_barrier(0);

  for (int jt = 0; jt < NT; ++jt){
    const int nb = (jt+1) & (NT-1);
    __builtin_amdgcn_sched_barrier(0);
    stage_slice16(Kbuf + ((jt+1)&1)*1024, Kg + (size_t)nb*64*HDIM, lane);  // [+2]
    stage_v(Vbuf + ((jt+1)&1)*1024, Vg + (size_t)nb*4096, lane);           // [+2]
    // steady state: loads(jt)[4, oldest] < stores(jt-1)[8] < loads(jt+1)[4]
    asm volatile("s_waitcnt vmcnt(12)" ::: "memory");  // K/V(jt) landed
    __builtin_amdgcn_sched_barrier(0);
    const bf16_t* kb = Kbuf + (jt&1)*1024;
    bf16x8_t kf0  = lds_read8(kb, qr, cg*8), kf1 = lds_read8(kb, qr, 32+cg*8);
    bf16x8_t k2f0 = sq8(kf0),                k2f1 = sq8(kf1);
    f32x4_t nu[2], nr[2];
    __builtin_amdgcn_s_setprio(1);
#pragma unroll
    for (int qh = 0; qh < 2; ++qh){
      f32x4_t a = {0.f,0.f,0.f,0.f}, b = {0.f,0.f,0.f,0.f};
      a = mfma16(aq[qh][0],  kf0,  a); a = mfma16(aq[qh][1],  kf1,  a);
      b = mfma16(aq2[qh][0], k2f0, b); b = mfma16(aq2[qh][1], k2f1, b);
      nu[qh] = a; nr[qh] = b;
    }
    __builtin_amdgcn_s_setprio(0);
#pragma unroll
    for (int qh = 0; qh < 2; ++qh)
#pragma unroll
      for (int r=0;r<4;r++){
        const float s = nu[qh][r]*rsqrtf(fmaxf(nr[qh][r], 6.4e-15f));
        const float wgt = __expf(s) * rl[qh][r];
        const int i = qt*32 + qh*16 + cg*4 + r;
        const int j = jt*64 + w*16 + qr;
        Wout[wb + (size_t)i*S_LEN + j] = wgt;                          // [8 stores]
        Pbuf[qh*384 + (cg*4+r)*24 + qr] = (bf16_t)wgt;
      }
    asm volatile("s_waitcnt lgkmcnt(0)" ::: "memory");  // P writes visible to own wave
    __builtin_amdgcn_sched_barrier(0);
    // PV: D[i,d] = sum_j P[i,j] V[j,d]; K=32 MFMA, A zero-padded on cg>=2
    const int k0 = (cg & 1) * 8;
    bf16x8_t pa0 = (cg < 2) ? *(const bf16x8_t*)&Pbuf[      qr*24 + k0] : zero8;
    bf16x8_t pa1 = (cg < 2) ? *(const bf16x8_t*)&Pbuf[384 + qr*24 + k0] : zero8;
    const bf16_t* vbase = Vbuf + (jt&1)*1024 + (cg&1)*512;   // jh = k0>>3
    __builtin_amdgcn_s_setprio(1);
#pragma unroll
    for (int n=0;n<4;n++){
      bf16x8_t vb = *(const bf16x8_t*)&vbase[(n*16+qr)*8];
      oacc[0][n] = mfma16(pa0, vb, oacc[0][n]);
      oacc[1][n] = mfma16(pa1, vb, oacc[1][n]);
    }
    __builtin_amdgcn_s_setprio(0);
  }

  // ---- O reduce across the 4 j-slice waves, then epilogue ----
  asm volatile("s_waitcnt vmcnt(0)" ::: "memory");      // drain wrap-stage DMA before reuse
  __builtin_amdgcn_sched_barrier(0);
  float* Ow = (float*)Kbuf;                             // own wave block, stride 68 (pad)
#pragma unroll
  for (int qh=0;qh<2;qh++)
#pragma unroll
    for (int n=0;n<4;n++)
#pragma unroll
      for (int r=0;r<4;r++)
        Ow[(qh*16+cg*4+r)*68 + n*16+qr] = oacc[qh][n][r];
  __syncthreads();                          // barrier #2
  {
    const int row = lane >> 1;              // 0..31
    const int jl  = (lane & 1)*8;
    float v[8];
#pragma unroll
    for (int e=0;e<8;e++) v[e] = 0.f;
#pragma unroll
    for (int ww=0; ww<4; ++ww){
      const float* Os = (const float*)(smem + ww*WBLK);
#pragma unroll
      for (int e=0;e<8;e++) v[e] += Os[row*68 + w*16 + jl + e];
    }
    const int b = bh >> 4, h = bh & 15;
    const int srow = qt*32 + row;
    const size_t o = ((size_t)b*S_LEN + srow)*DMODEL + (size_t)h*HDIM + w*16 + jl;
    bf16x8_t hv;
#pragma unroll
    for (int e=0;e<8;e++) hv[e] = (bf16_t)v[e];
    *(bf16x8_t*)(o1 + o) = hv;
  }
}

// ---------------- K3: output projection, plain bf16, 64x128 tile ----------------
// grid (64, 8) = 512 WGs -> 2 WG/CU co-resident. Each wave: 64 rows x 32 cols.
__global__ __launch_bounds__(256)
void vsa_oproj_kernel(const bf16_t* __restrict__ Ab, const bf16_t* __restrict__ Bb,
                      float* __restrict__ out)
{
  __shared__ __align__(16) bf16_t Ah[64][64], Bh[128][64];
  const int m0 = blockIdx.x * 64;
  const int n0 = blockIdx.y * 128;
  const int tid = threadIdx.x, lane = tid & 63, wid = tid >> 6;
  const int wc = wid * 32;

  const f32x4_t zz = {0.f,0.f,0.f,0.f};
  f32x4_t acc[4][2];
#pragma unroll
  for (int i=0;i<4;i++)
#pragma unroll
    for (int j=0;j<2;j++) acc[i][j] = zz;

  for (int kt = 0; kt < 16; ++kt){
    const int k0 = kt * 64;
    stage_tile<64> (&Ah[0][0], Ab + (size_t)m0*DMODEL + k0, DMODEL, wid, lane);
    stage_tile<128>(&Bh[0][0], Bb + (size_t)n0*DMODEL + k0, DMODEL, wid, lane);
    __syncthreads();
#pragma unroll
    for (int kk = 0; kk < 2; ++kk){
      const int ko = kk*32 + (lane>>4)*8;
      bf16x8_t ah[4], bh4[2];
#pragma unroll
      for (int i=0;i<4;i++)
        ah[i] = lds_read8(&Ah[0][0], i*16 + (lane&15), ko);
#pragma unroll
      for (int j=0;j<2;j++)
        bh4[j] = lds_read8(&Bh[0][0], wc + j*16 + (lane&15), ko);
#pragma unroll
      for (int i=0;i<4;i++)
#pragma unroll
        for (int j=0;j<2;j++)
          acc[i][j] = mfma16(ah[i], bh4[j], acc[i][j]);
    }
    __syncthreads();
  }

#pragma unroll
  for (int i=0;i<4;i++)
#pragma unroll
    for (int j=0;j<2;j++)
#pragma unroll
      for (int r=0;r<4;r++){
        const int m = m0 + i*16 + ((lane>>4)<<2) + r;
        const int n = n0 + wc + j*16 + (lane&15);
        out[(size_t)m*DMODEL + n] = acc[i][j][r];
      }
}

extern "C" void kernel_launch(void* const* d_in, const int* in_sizes, int n_in,
                              void* d_out, int out_size, void* d_ws, size_t ws_size,
                              hipStream_t stream)
{
  const float* x  = (const float*)d_in[0];
  const float* Wq = (const float*)d_in[1];
  const float* Wk = (const float*)d_in[2];
  const float* Wv = (const float*)d_in[3];
  const float* Wo = (const float*)d_in[4];
  float* out  = (float*)d_out;
  float* attw = out + (size_t)MTOT*DMODEL;   // tuple output 1: [B,H,S,S]

  // workspace layout (bf16 elements, each slab 4194304 elts = 8 MB)
  bf16_t* ws = (bf16_t*)d_ws;
  const size_t C = 4194304;
  bf16_t* xb   = ws;
  bf16_t* Wb   = ws + C;     // [4][1024*1024] order q,k,v,o
  bf16_t* Qb   = ws + 2*C;
  bf16_t* Kb   = ws + 3*C;
  bf16_t* Vblk = ws + 4*C;
  bf16_t* o1   = ws + 5*C;

  const int W1 = DMODEL*DMODEL; // 1048576
  vsa_cast_kernel<<<(int)(C/1024), 256, 0, stream>>>(x,  xb, (int)(C/4));
  vsa_cast_kernel<<<W1/1024, 256, 0, stream>>>(Wq, Wb + 0*(size_t)W1, W1/4);
  vsa_cast_kernel<<<W1/1024, 256, 0, stream>>>(Wk, Wb + 1*(size_t)W1, W1/4);
  vsa_cast_kernel<<<W1/1024, 256, 0, stream>>>(Wv, Wb + 2*(size_t)W1, W1/4);
  vsa_cast_kernel<<<W1/1024, 256, 0, stream>>>(Wo, Wb + 3*(size_t)W1, W1/4);

  vsa_qkv_kernel<<<dim3(32, 8, 3), 256, 0, stream>>>(xb, Wb, Qb, Kb, Vblk);
  vsa_attn_kernel<<<dim3(2048), 256, 0, stream>>>(Qb, Kb, Vblk, attw, o1);
  vsa_oproj_kernel<<<dim3(64, 8), 256, 0, stream>>>(o1, Wb + 3*(size_t)W1, out);
}